// Round 6
// baseline (538.559 us; speedup 1.0000x reference)
//
#include <hip/hip_runtime.h>
#include <hip/hip_bf16.h>

#define NN     14848      // nodes
#define NE     475136     // edges
#define NROI   116        // nodes per graph
#define NGRAPH 128        // graphs
#define EPG    3712       // edges per graph (116*32)
#define HID    64
#define HC     256
#define NEG    0.01f
#define NEGA   0.2f
#define EPB    2048       // max edges per half-graph block (mean 1856, +6.3 sigma)
#define XPAD   68         // Xs row stride: even*4 for 16B-aligned b128, 68%32=4 spreads banks

typedef __attribute__((ext_vector_type(8))) short short8;
typedef __attribute__((ext_vector_type(4))) float floatx4;

__device__ __forceinline__ float leaky(float x, float s) { return x >= 0.f ? x : s * x; }

// round-to-nearest-even float -> bf16 bits
__device__ __forceinline__ short f2bf(float f) {
    unsigned u = __float_as_uint(f);
    unsigned r = (u + 0x7fffu + ((u >> 16) & 1u)) >> 16;
    return (short)r;
}

// ---------------------------------------------------------------- embed
__global__ __launch_bounds__(64) void k_embed(
    const float* __restrict__ x, const int* __restrict__ ng,
    const float* __restrict__ gemb, const float* __restrict__ W,
    const float* __restrict__ b, float* __restrict__ h0)
{
    const int n = blockIdx.x, c = threadIdx.x;
    __shared__ float in[132];
    for (int k = c; k < NROI; k += 64) in[k] = x[n * NROI + k];
    if (c < 16) in[NROI + c] = gemb[ng[n] * 16 + c];
    __syncthreads();
    float acc = b[c];
    #pragma unroll 4
    for (int k = 0; k < 132; k++) acc = fmaf(in[k], W[k * 64 + c], acc);
    h0[n * 64 + c] = leaky(acc, NEG);
}

// ---------------------------------------------------------------- CSR build (counting sort by dst, per graph)
__global__ __launch_bounds__(256) void k_csr(
    const int* __restrict__ src, const int* __restrict__ dst,
    const float* __restrict__ ea,
    int* __restrict__ row_start, int* __restrict__ row_cnt,
    int* __restrict__ ssd, float* __restrict__ ea_s)
{
    const int g = blockIdx.x, tid = threadIdx.x;
    const int e0 = g * EPG, nb = g * NROI;
    __shared__ int cnt[NROI], start[NROI], cur[NROI];
    if (tid < NROI) cnt[tid] = 0;
    __syncthreads();
    for (int i = tid; i < EPG; i += 256) atomicAdd(&cnt[dst[e0 + i] - nb], 1);
    __syncthreads();
    if (tid == 0) {
        int s = 0;
        for (int r = 0; r < NROI; r++) { start[r] = s; s += cnt[r]; }
    }
    __syncthreads();
    if (tid < NROI) {
        row_start[nb + tid] = e0 + start[tid];
        row_cnt[nb + tid] = cnt[tid];
        cur[tid] = start[tid];
    }
    __syncthreads();
    for (int i = tid; i < EPG; i += 256) {
        const int e = e0 + i, dl = dst[e] - nb;
        const int pos = atomicAdd(&cur[dl], 1);
        const int gi = e0 + pos;
        ssd[gi] = (src[e] - nb) | (dl << 16);
        const float4 q = make_float4(ea[e * 5], ea[e * 5 + 1], ea[e * 5 + 2], ea[e * 5 + 3]);
        *(float4*)&ea_s[(size_t)gi * 8] = q;
        ea_s[(size_t)gi * 8 + 4] = ea[e * 5 + 4];
    }
}

// ---------------------------------------------------------------- weight prep: Wt[n][k] = bf16(concat(Wl,Wr)[k][n])
template <int D>
__global__ __launch_bounds__(64) void k_prep_w(
    const float* __restrict__ Wl, const float* __restrict__ Wr,
    short* __restrict__ Wt)
{
    const int n = blockIdx.x;
    for (int k = threadIdx.x; k < D; k += 64) {
        const float v = (n < 256) ? Wl[k * 256 + n] : Wr[k * 256 + (n - 256)];
        Wt[(size_t)n * D + k] = f2bf(v);
    }
}

// ---------------------------------------------------------------- GINE (CSR, per-row wave) fused with MLP + LayerNorm -> bf16
__global__ __launch_bounds__(256) void k_gine_mlp_ln(
    const float* __restrict__ h0, const int* __restrict__ row_start,
    const int* __restrict__ row_cnt, const int* __restrict__ ssd,
    const float* __restrict__ ea_s,
    const float* __restrict__ We, const float* __restrict__ be,
    const float* __restrict__ W1, const float* __restrict__ b1,
    const float* __restrict__ W2, const float* __restrict__ b2,
    const float* __restrict__ lg_, const float* __restrict__ lb_,
    short* __restrict__ hn)
{
    const int tid = threadIdx.x, w = tid >> 6, lane = tid & 63;
    const int row = blockIdx.x * 4 + w;
    const int nb = (row / NROI) * NROI;
    const int st = row_start[row], cnt = row_cnt[row];
    const float w0 = We[lane], w1 = We[64 + lane], w2 = We[128 + lane],
                w3 = We[192 + lane], w4 = We[256 + lane];
    const float bec = be[lane];
    float g0 = 0.f, g1 = 0.f;
    int j = 0;
    for (; j + 2 <= cnt; j += 2) {
        const int ia = st + j, ib = st + j + 1;
        const int sa = nb + (ssd[ia] & 0xffff), sb = nb + (ssd[ib] & 0xffff);
        const float4 qa = *(const float4*)&ea_s[(size_t)ia * 8];
        const float qa4 = ea_s[(size_t)ia * 8 + 4];
        const float4 qb = *(const float4*)&ea_s[(size_t)ib * 8];
        const float qb4 = ea_s[(size_t)ib * 8 + 4];
        float ea_ = bec, eb_ = bec;
        ea_ = fmaf(qa.x, w0, ea_); eb_ = fmaf(qb.x, w0, eb_);
        ea_ = fmaf(qa.y, w1, ea_); eb_ = fmaf(qb.y, w1, eb_);
        ea_ = fmaf(qa.z, w2, ea_); eb_ = fmaf(qb.z, w2, eb_);
        ea_ = fmaf(qa.w, w3, ea_); eb_ = fmaf(qb.w, w3, eb_);
        ea_ = fmaf(qa4, w4, ea_);  eb_ = fmaf(qb4, w4, eb_);
        g0 += fmaxf(h0[sa * 64 + lane] + leaky(ea_, NEG), 0.f);
        g1 += fmaxf(h0[sb * 64 + lane] + leaky(eb_, NEG), 0.f);
    }
    for (; j < cnt; j++) {
        const int idx = st + j;
        const int s = nb + (ssd[idx] & 0xffff);
        const float4 q = *(const float4*)&ea_s[(size_t)idx * 8];
        const float q4 = ea_s[(size_t)idx * 8 + 4];
        float em = bec;
        em = fmaf(q.x, w0, em); em = fmaf(q.y, w1, em); em = fmaf(q.z, w2, em);
        em = fmaf(q.w, w3, em); em = fmaf(q4, w4, em);
        g0 += fmaxf(h0[s * 64 + lane] + leaky(em, NEG), 0.f);
    }
    const float aggv = g0 + g1;
    __shared__ float v[4][64], t[4][64];
    v[w][lane] = h0[row * 64 + lane] + aggv;
    __syncthreads();
    float a = b1[lane];
    #pragma unroll 8
    for (int k = 0; k < 64; k++) a = fmaf(v[w][k], W1[k * 64 + lane], a);
    t[w][lane] = leaky(a, NEG);
    __syncthreads();
    float o = b2[lane];
    #pragma unroll 8
    for (int k = 0; k < 64; k++) o = fmaf(t[w][k], W2[k * 64 + lane], o);
    o = leaky(o, NEG);
    float s = o;
    #pragma unroll
    for (int off = 32; off; off >>= 1) s += __shfl_xor(s, off);
    const float mu = s * (1.f / 64.f);
    const float d = o - mu;
    float s2 = d * d;
    #pragma unroll
    for (int off = 32; off; off >>= 1) s2 += __shfl_xor(s2, off);
    hn[row * 64 + lane] = f2bf(d * rsqrtf(s2 * (1.f / 64.f) + 1e-5f) * lg_[lane] + lb_[lane]);
}

// ---------------------------------------------------------------- BN apply + leaky -> bf16 (layer-1 GEMM input)
__global__ __launch_bounds__(256) void k_bn_bf16(
    const float* __restrict__ V, const float* __restrict__ stats,
    const float* __restrict__ bg, const float* __restrict__ bb,
    short* __restrict__ Hb)
{
    const int n = blockIdx.x, c = threadIdx.x;
    const float inv_n = 1.f / (float)NN;
    const float mu = stats[c] * inv_n;
    float var = stats[256 + c] * inv_n - mu * mu;
    var = fmaxf(var, 0.f);
    const float rsg = rsqrtf(var + 1e-5f) * bg[c];
    const float o = (V[(size_t)n * HC + c] - mu) * rsg + bb[c];
    Hb[(size_t)n * HC + c] = f2bf(leaky(o, NEG));
}

// ---------------------------------------------------------------- MFMA bf16 GEMM: [NN x D] @ [D x 512] -> X | Y (fp32)
// A row-major k-contiguous; Wt n-major k-contiguous (= B^T input).
// mfma_f32_16x16x32_bf16: A[m=lane&15][k=(lane>>4)*8+j]; B[k=(lane>>4)*8+j][n=lane&15];
// D: col=lane&15, row=(lane>>4)*4+reg   [m89-verified layouts]
template <int D>
__global__ __launch_bounds__(256) void k_gemm(
    const short* __restrict__ A, const short* __restrict__ Wt,
    float* __restrict__ X, float* __restrict__ Y)
{
    const int m0 = blockIdx.x * 16;
    const int w = threadIdx.x >> 6, lane = threadIdx.x & 63;
    const int n0 = w * 128;                     // waves 0,1 -> X; 2,3 -> Y
    const int r = lane & 15, q = lane >> 4;
    floatx4 acc[8];
    #pragma unroll
    for (int t = 0; t < 8; t++) acc[t] = (floatx4){0.f, 0.f, 0.f, 0.f};
    const short* Arow = A + (size_t)(m0 + r) * D + q * 8;
    const short* Brow = Wt + (size_t)(n0 + r) * D + q * 8;
    #pragma unroll
    for (int k0 = 0; k0 < D; k0 += 32) {
        const short8 a = *(const short8*)(Arow + k0);
        #pragma unroll
        for (int t = 0; t < 8; t++) {
            const short8 b = *(const short8*)(Brow + (size_t)t * 16 * D + k0);
            acc[t] = __builtin_amdgcn_mfma_f32_16x16x32_bf16(a, b, acc[t], 0, 0, 0);
        }
    }
    #pragma unroll
    for (int t = 0; t < 8; t++) {
        const int ncol = n0 + t * 16 + r;
        #pragma unroll
        for (int g2 = 0; g2 < 4; g2++) {
            const int row = m0 + q * 4 + g2;
            if (ncol < 256) X[(size_t)row * HC + ncol] = acc[t][g2];
            else            Y[(size_t)row * HC + (ncol - 256)] = acc[t][g2];
        }
    }
}

// ---------------------------------------------------------------- fused GATv2: block = (graph, head, half)
// A: lane=edge logits (float4 X/Y); B: per-row max/exp/sum -> inv; C: numerator*inv + BN partials
__global__ __launch_bounds__(256, 4) void k_gat(
    const int* __restrict__ row_start, const int* __restrict__ row_cnt,
    const int* __restrict__ ssd, const float* __restrict__ ea_s,
    const float* __restrict__ We, const float* __restrict__ att,
    const float* __restrict__ bias,
    const float* __restrict__ X, const float* __restrict__ Y,
    float* __restrict__ V, float* __restrict__ stats)
{
    const int g = blockIdx.x >> 3;
    const int h = (blockIdx.x >> 1) & 3;
    const int half = blockIdx.x & 1;
    const int tid = threadIdx.x, w = tid >> 6, lane = tid & 63;
    const int nb = g * NROI, e0 = g * EPG, hc = h * 64;
    const int r0 = half * 58, r1 = r0 + 58;
    const int es = row_start[nb + r0];
    const int ee = (r1 < NROI) ? row_start[nb + r1] : e0 + EPG;

    __shared__ float Xs[NROI * XPAD];
    __shared__ float lg[EPB];
    __shared__ float inv_s[58];

    for (int r = w; r < NROI; r += 4)
        Xs[r * XPAD + lane] = X[(size_t)(nb + r) * HC + hc + lane];
    __syncthreads();

    // ---- phase A: logits, lane = edge, float4 over channels
    const int ne = ee - es;
    for (int i = tid; i < ne; i += 256) {
        const int e = es + i;
        const int sd = ssd[e];
        const int sl = sd & 0xffff, dl = sd >> 16;
        const float4 q = *(const float4*)&ea_s[(size_t)e * 8];
        const float q4 = ea_s[(size_t)e * 8 + 4];
        const float* yrow = &Y[(size_t)(nb + dl) * HC + hc];
        float a0 = 0.f, a1 = 0.f, a2 = 0.f, a3 = 0.f;
        for (int c = 0; c < 64; c += 4) {
            const float4 y4 = *(const float4*)(yrow + c);
            const float4 x4 = *(const float4*)&Xs[sl * XPAD + c];
            float e0_ = q.x * We[0 * HC + hc + c + 0];
            e0_ = fmaf(q.y, We[1 * HC + hc + c + 0], e0_);
            e0_ = fmaf(q.z, We[2 * HC + hc + c + 0], e0_);
            e0_ = fmaf(q.w, We[3 * HC + hc + c + 0], e0_);
            e0_ = fmaf(q4, We[4 * HC + hc + c + 0], e0_);
            float e1_ = q.x * We[0 * HC + hc + c + 1];
            e1_ = fmaf(q.y, We[1 * HC + hc + c + 1], e1_);
            e1_ = fmaf(q.z, We[2 * HC + hc + c + 1], e1_);
            e1_ = fmaf(q.w, We[3 * HC + hc + c + 1], e1_);
            e1_ = fmaf(q4, We[4 * HC + hc + c + 1], e1_);
            float e2_ = q.x * We[0 * HC + hc + c + 2];
            e2_ = fmaf(q.y, We[1 * HC + hc + c + 2], e2_);
            e2_ = fmaf(q.z, We[2 * HC + hc + c + 2], e2_);
            e2_ = fmaf(q.w, We[3 * HC + hc + c + 2], e2_);
            e2_ = fmaf(q4, We[4 * HC + hc + c + 2], e2_);
            float e3_ = q.x * We[0 * HC + hc + c + 3];
            e3_ = fmaf(q.y, We[1 * HC + hc + c + 3], e3_);
            e3_ = fmaf(q.z, We[2 * HC + hc + c + 3], e3_);
            e3_ = fmaf(q.w, We[3 * HC + hc + c + 3], e3_);
            e3_ = fmaf(q4, We[4 * HC + hc + c + 3], e3_);
            const float z0 = x4.x + y4.x + e0_;
            const float z1 = x4.y + y4.y + e1_;
            const float z2 = x4.z + y4.z + e2_;
            const float z3 = x4.w + y4.w + e3_;
            a0 = fmaf(att[hc + c + 0], leaky(z0, NEGA), a0);
            a1 = fmaf(att[hc + c + 1], leaky(z1, NEGA), a1);
            a2 = fmaf(att[hc + c + 2], leaky(z2, NEGA), a2);
            a3 = fmaf(att[hc + c + 3], leaky(z3, NEGA), a3);
        }
        lg[i] = (a0 + a1) + (a2 + a3);
    }
    __syncthreads();

    // ---- phase B: per-row max / exp / sum; store reciprocal
    for (int r = r0 + w; r < r1; r += 4) {
        const int stl = row_start[nb + r] - es;
        const int cnt = row_cnt[nb + r];
        float m = -INFINITY;
        for (int j = lane; j < cnt; j += 64) m = fmaxf(m, lg[stl + j]);
        #pragma unroll
        for (int off = 32; off; off >>= 1) m = fmaxf(m, __shfl_xor(m, off));
        float s = 0.f;
        for (int j = lane; j < cnt; j += 64) {
            const float e_ = __expf(lg[stl + j] - m);
            lg[stl + j] = e_;
            s += e_;
        }
        #pragma unroll
        for (int off = 32; off; off >>= 1) s += __shfl_xor(s, off);
        if (lane == 0) inv_s[r - r0] = 1.f / (s + 1e-16f);
    }
    __syncthreads();

    // ---- phase C: numerator (wave per row, lane = channel) + BN partials
    float ps = 0.f, ps2 = 0.f;
    const float bb = bias[hc + lane];
    for (int r = r0 + w; r < r1; r += 4) {
        const int st = row_start[nb + r];
        const int cnt = row_cnt[nb + r];
        const int stl = st - es;
        float a0 = 0.f, a1 = 0.f, a2 = 0.f, a3 = 0.f;
        int j = 0;
        for (; j + 4 <= cnt; j += 4) {
            const int s0 = ssd[st + j] & 0xffff, s1 = ssd[st + j + 1] & 0xffff,
                      s2 = ssd[st + j + 2] & 0xffff, s3 = ssd[st + j + 3] & 0xffff;
            a0 = fmaf(Xs[s0 * XPAD + lane], lg[stl + j], a0);
            a1 = fmaf(Xs[s1 * XPAD + lane], lg[stl + j + 1], a1);
            a2 = fmaf(Xs[s2 * XPAD + lane], lg[stl + j + 2], a2);
            a3 = fmaf(Xs[s3 * XPAD + lane], lg[stl + j + 3], a3);
        }
        for (; j < cnt; j++)
            a0 = fmaf(Xs[(ssd[st + j] & 0xffff) * XPAD + lane], lg[stl + j], a0);
        const float vv = ((a0 + a1) + (a2 + a3)) * inv_s[r - r0] + bb;
        V[(size_t)(nb + r) * HC + hc + lane] = vv;
        ps += vv;
        ps2 += vv * vv;
    }
    __syncthreads();                 // lg free; reuse as reduction buffer
    lg[tid] = ps;
    lg[256 + tid] = ps2;
    __syncthreads();
    if (tid < 64) {
        float s1 = 0.f, s2 = 0.f;
        #pragma unroll
        for (int w2 = 0; w2 < 4; w2++) {
            s1 += lg[w2 * 64 + tid];
            s2 += lg[256 + w2 * 64 + tid];
        }
        atomicAdd(&stats[hc + tid], s1);
        atomicAdd(&stats[256 + hc + tid], s2);
    }
}

// ---------------------------------------------------------------- BN + leaky + mean-pool + classifier
__global__ __launch_bounds__(256) void k_pool_fc(
    const float* __restrict__ V, const float* __restrict__ stats,
    const float* __restrict__ bg, const float* __restrict__ bb,
    const float* __restrict__ fW, const float* __restrict__ fb,
    float* __restrict__ out)
{
    const int g = blockIdx.x, c = threadIdx.x;
    const float inv_n = 1.f / (float)NN;
    const float mu = stats[c] * inv_n;
    float var = stats[256 + c] * inv_n - mu * mu;
    var = fmaxf(var, 0.f);
    const float rsg = rsqrtf(var + 1e-5f) * bg[c];
    const float bbc = bb[c];
    float s = 0.f;
    for (int r = 0; r < NROI; r++) {
        const float vv = (V[(size_t)(g * NROI + r) * HC + c] - mu) * rsg + bbc;
        s += leaky(vv, NEG);
    }
    s *= (1.f / (float)NROI);
    __shared__ float red[256];
    for (int o = 0; o < 2; o++) {
        red[c] = s * fW[c * 2 + o];
        __syncthreads();
        for (int off = 128; off; off >>= 1) {
            if (c < off) red[c] += red[c + off];
            __syncthreads();
        }
        if (c == 0) out[g * 2 + o] = red[0] + fb[o];
        __syncthreads();
    }
}

extern "C" void kernel_launch(void* const* d_in, const int* in_sizes, int n_in,
                              void* d_out, int out_size, void* d_ws, size_t ws_size,
                              hipStream_t stream) {
    const float* x         = (const float*)d_in[0];
    const int*   edge_idx  = (const int*)d_in[1];
    const float* edge_attr = (const float*)d_in[2];
    const int*   node_grp  = (const int*)d_in[4];
    const float* group_emb = (const float*)d_in[5];
    const float* W_embed   = (const float*)d_in[6];
    const float* b_embed   = (const float*)d_in[7];
    const float* We_enc    = (const float*)d_in[8];
    const float* be_enc    = (const float*)d_in[9];
    const float* W1        = (const float*)d_in[10];
    const float* b1        = (const float*)d_in[11];
    const float* W2        = (const float*)d_in[12];
    const float* b2        = (const float*)d_in[13];
    const float* ln_g      = (const float*)d_in[14];
    const float* ln_b      = (const float*)d_in[15];
    const float* l0_Wl     = (const float*)d_in[16];
    const float* l0_Wr     = (const float*)d_in[17];
    const float* l0_We     = (const float*)d_in[18];
    const float* l0_att    = (const float*)d_in[19];
    const float* l0_b      = (const float*)d_in[20];
    const float* l0_bn_g   = (const float*)d_in[21];
    const float* l0_bn_b   = (const float*)d_in[22];
    const float* l1_Wl     = (const float*)d_in[23];
    const float* l1_Wr     = (const float*)d_in[24];
    const float* l1_We     = (const float*)d_in[25];
    const float* l1_att    = (const float*)d_in[26];
    const float* l1_b      = (const float*)d_in[27];
    const float* l1_bn_g   = (const float*)d_in[28];
    const float* l1_bn_b   = (const float*)d_in[29];
    const float* fc2_W     = (const float*)d_in[30];
    const float* fc2_b     = (const float*)d_in[31];

    const int* src = edge_idx;
    const int* dst = edge_idx + NE;

    float* ws     = (float*)d_ws;
    float* h0     = ws;                       // 64*NN f32
    float* X      = h0 + (size_t)64 * NN;     // 256*NN f32
    float* Y      = X + (size_t)HC * NN;      // 256*NN f32
    float* V      = Y + (size_t)HC * NN;      // 256*NN f32
    float* stats0 = V + (size_t)HC * NN;      // 512
    float* stats1 = stats0 + 512;             // 512
    float* ea_s   = stats1 + 512;             // 8*NE f32
    int* row_start = (int*)(ea_s + (size_t)8 * NE);  // NN
    int* row_cnt   = row_start + NN;                 // NN
    int* ssd       = row_cnt + NN;                   // NE
    short* hn_b    = (short*)(ssd + NE);             // 64*NN bf16
    short* Hb1     = hn_b + (size_t)64 * NN;         // 256*NN bf16
    short* Wt0     = Hb1 + (size_t)HC * NN;          // 512*64 bf16
    short* Wt1     = Wt0 + 512 * 64;                 // 512*256 bf16

    float* out = (float*)d_out;

    hipMemsetAsync(stats0, 0, 1024 * sizeof(float), stream);  // stats0 + stats1
    k_embed<<<NN, 64, 0, stream>>>(x, node_grp, group_emb, W_embed, b_embed, h0);
    k_csr<<<NGRAPH, 256, 0, stream>>>(src, dst, edge_attr, row_start, row_cnt, ssd, ea_s);
    k_prep_w<64><<<512, 64, 0, stream>>>(l0_Wl, l0_Wr, Wt0);
    k_prep_w<256><<<512, 64, 0, stream>>>(l1_Wl, l1_Wr, Wt1);
    k_gine_mlp_ln<<<NN / 4, 256, 0, stream>>>(h0, row_start, row_cnt, ssd, ea_s,
                                              We_enc, be_enc, W1, b1, W2, b2, ln_g, ln_b, hn_b);

    // GAT layer 0
    k_gemm<64><<<NN / 16, 256, 0, stream>>>(hn_b, Wt0, X, Y);
    k_gat<<<NGRAPH * 8, 256, 0, stream>>>(row_start, row_cnt, ssd, ea_s,
                                          l0_We, l0_att, l0_b, X, Y, V, stats0);

    // GAT layer 1
    k_bn_bf16<<<NN, 256, 0, stream>>>(V, stats0, l0_bn_g, l0_bn_b, Hb1);
    k_gemm<256><<<NN / 16, 256, 0, stream>>>(Hb1, Wt1, X, Y);
    k_gat<<<NGRAPH * 8, 256, 0, stream>>>(row_start, row_cnt, ssd, ea_s,
                                          l1_We, l1_att, l1_b, X, Y, V, stats1);

    // BN+leaky of layer-1 output fused into pooling
    k_pool_fc<<<NGRAPH, 256, 0, stream>>>(V, stats1, l1_bn_g, l1_bn_b, fc2_W, fc2_b, out);
}

// Round 7
// 454.124 us; speedup vs baseline: 1.1859x; 1.1859x over previous
//
#include <hip/hip_runtime.h>
#include <hip/hip_bf16.h>

#define NN     14848      // nodes
#define NE     475136     // edges
#define NROI   116        // nodes per graph
#define NGRAPH 128        // graphs
#define EPG    3712       // edges per graph (116*32)
#define HID    64
#define HC     256
#define NEG    0.01f
#define NEGA   0.2f
#define EPB    2304       // max edges per half-graph block (mean 1856)
#define XPAD   65         // Xs row stride (R5-measured best)

typedef __attribute__((ext_vector_type(8))) short short8;
typedef __attribute__((ext_vector_type(4))) float floatx4;

// leaky(x) = max(x, s*x) for 0<s<1 — 2 VALU, no branch
__device__ __forceinline__ float leaky(float x, float s) { return fmaxf(x, s * x); }

// round-to-nearest-even float -> bf16 bits
__device__ __forceinline__ short f2bf(float f) {
    unsigned u = __float_as_uint(f);
    unsigned r = (u + 0x7fffu + ((u >> 16) & 1u)) >> 16;
    return (short)r;
}

// ---------------------------------------------------------------- embed (4 nodes/block)
__global__ __launch_bounds__(256) void k_embed(
    const float* __restrict__ x, const int* __restrict__ ng,
    const float* __restrict__ gemb, const float* __restrict__ W,
    const float* __restrict__ b, float* __restrict__ h0)
{
    const int w = threadIdx.x >> 6, c = threadIdx.x & 63;
    const int n = blockIdx.x * 4 + w;
    __shared__ float in[4][132];
    for (int k = c; k < NROI; k += 64) in[w][k] = x[n * NROI + k];
    if (c < 16) in[w][NROI + c] = gemb[ng[n] * 16 + c];
    __syncthreads();
    float acc = b[c];
    #pragma unroll 4
    for (int k = 0; k < 132; k++) acc = fmaf(in[w][k], W[k * 64 + c], acc);
    h0[n * 64 + c] = leaky(acc, NEG);
}

// ---------------------------------------------------------------- CSR build (counting sort by dst, per graph)
__global__ __launch_bounds__(256) void k_csr(
    const int* __restrict__ src, const int* __restrict__ dst,
    const float* __restrict__ ea,
    int* __restrict__ row_start, int* __restrict__ row_cnt,
    int* __restrict__ ssd, float* __restrict__ ea_s)
{
    const int g = blockIdx.x, tid = threadIdx.x;
    const int e0 = g * EPG, nb = g * NROI;
    __shared__ int cnt[NROI], start[NROI], cur[NROI];
    if (tid < NROI) cnt[tid] = 0;
    __syncthreads();
    for (int i = tid; i < EPG; i += 256) atomicAdd(&cnt[dst[e0 + i] - nb], 1);
    __syncthreads();
    if (tid == 0) {
        int s = 0;
        for (int r = 0; r < NROI; r++) { start[r] = s; s += cnt[r]; }
    }
    __syncthreads();
    if (tid < NROI) {
        row_start[nb + tid] = e0 + start[tid];
        row_cnt[nb + tid] = cnt[tid];
        cur[tid] = start[tid];
    }
    __syncthreads();
    for (int i = tid; i < EPG; i += 256) {
        const int e = e0 + i, dl = dst[e] - nb;
        const int pos = atomicAdd(&cur[dl], 1);
        const int gi = e0 + pos;
        ssd[gi] = (src[e] - nb) | (dl << 16);
        const float4 q = make_float4(ea[e * 5], ea[e * 5 + 1], ea[e * 5 + 2], ea[e * 5 + 3]);
        *(float4*)&ea_s[(size_t)gi * 8] = q;
        ea_s[(size_t)gi * 8 + 4] = ea[e * 5 + 4];
    }
}

// ---------------------------------------------------------------- weight prep (both layers, one launch)
// blocks 0..511: Wt0[n][k]=bf16(l0 concat(Wl,Wr)[k][n]) D=64; blocks 512..1023: Wt1, D=256
__global__ __launch_bounds__(64) void k_prep_w(
    const float* __restrict__ Wl0, const float* __restrict__ Wr0,
    const float* __restrict__ Wl1, const float* __restrict__ Wr1,
    short* __restrict__ Wt0, short* __restrict__ Wt1)
{
    if (blockIdx.x < 512) {
        const int n = blockIdx.x;
        for (int k = threadIdx.x; k < 64; k += 64) {
            const float v = (n < 256) ? Wl0[k * 256 + n] : Wr0[k * 256 + (n - 256)];
            Wt0[(size_t)n * 64 + k] = f2bf(v);
        }
    } else {
        const int n = blockIdx.x - 512;
        for (int k = threadIdx.x; k < 256; k += 64) {
            const float v = (n < 256) ? Wl1[k * 256 + n] : Wr1[k * 256 + (n - 256)];
            Wt1[(size_t)n * 256 + k] = f2bf(v);
        }
    }
}

// ---------------------------------------------------------------- GINE (CSR, per-row wave) fused with MLP + LayerNorm -> bf16
__global__ __launch_bounds__(256) void k_gine_mlp_ln(
    const float* __restrict__ h0, const int* __restrict__ row_start,
    const int* __restrict__ row_cnt, const int* __restrict__ ssd,
    const float* __restrict__ ea_s,
    const float* __restrict__ We, const float* __restrict__ be,
    const float* __restrict__ W1, const float* __restrict__ b1,
    const float* __restrict__ W2, const float* __restrict__ b2,
    const float* __restrict__ lg_, const float* __restrict__ lb_,
    short* __restrict__ hn)
{
    const int tid = threadIdx.x, w = tid >> 6, lane = tid & 63;
    const int row = blockIdx.x * 4 + w;
    const int nb = (row / NROI) * NROI;
    const int st = row_start[row], cnt = row_cnt[row];
    const float w0 = We[lane], w1 = We[64 + lane], w2 = We[128 + lane],
                w3 = We[192 + lane], w4 = We[256 + lane];
    const float bec = be[lane];
    float g0 = 0.f, g1 = 0.f;
    int j = 0;
    for (; j + 2 <= cnt; j += 2) {
        const int ia = st + j, ib = st + j + 1;
        const int sa = nb + (ssd[ia] & 0xffff), sb = nb + (ssd[ib] & 0xffff);
        const float4 qa = *(const float4*)&ea_s[(size_t)ia * 8];
        const float qa4 = ea_s[(size_t)ia * 8 + 4];
        const float4 qb = *(const float4*)&ea_s[(size_t)ib * 8];
        const float qb4 = ea_s[(size_t)ib * 8 + 4];
        float ea_ = bec, eb_ = bec;
        ea_ = fmaf(qa.x, w0, ea_); eb_ = fmaf(qb.x, w0, eb_);
        ea_ = fmaf(qa.y, w1, ea_); eb_ = fmaf(qb.y, w1, eb_);
        ea_ = fmaf(qa.z, w2, ea_); eb_ = fmaf(qb.z, w2, eb_);
        ea_ = fmaf(qa.w, w3, ea_); eb_ = fmaf(qb.w, w3, eb_);
        ea_ = fmaf(qa4, w4, ea_);  eb_ = fmaf(qb4, w4, eb_);
        g0 += fmaxf(h0[sa * 64 + lane] + leaky(ea_, NEG), 0.f);
        g1 += fmaxf(h0[sb * 64 + lane] + leaky(eb_, NEG), 0.f);
    }
    for (; j < cnt; j++) {
        const int idx = st + j;
        const int s = nb + (ssd[idx] & 0xffff);
        const float4 q = *(const float4*)&ea_s[(size_t)idx * 8];
        const float q4 = ea_s[(size_t)idx * 8 + 4];
        float em = bec;
        em = fmaf(q.x, w0, em); em = fmaf(q.y, w1, em); em = fmaf(q.z, w2, em);
        em = fmaf(q.w, w3, em); em = fmaf(q4, w4, em);
        g0 += fmaxf(h0[s * 64 + lane] + leaky(em, NEG), 0.f);
    }
    const float aggv = g0 + g1;
    __shared__ float v[4][64], t[4][64];
    v[w][lane] = h0[row * 64 + lane] + aggv;
    __syncthreads();
    float a = b1[lane];
    #pragma unroll 8
    for (int k = 0; k < 64; k++) a = fmaf(v[w][k], W1[k * 64 + lane], a);
    t[w][lane] = leaky(a, NEG);
    __syncthreads();
    float o = b2[lane];
    #pragma unroll 8
    for (int k = 0; k < 64; k++) o = fmaf(t[w][k], W2[k * 64 + lane], o);
    o = leaky(o, NEG);
    float s = o;
    #pragma unroll
    for (int off = 32; off; off >>= 1) s += __shfl_xor(s, off);
    const float mu = s * (1.f / 64.f);
    const float d = o - mu;
    float s2 = d * d;
    #pragma unroll
    for (int off = 32; off; off >>= 1) s2 += __shfl_xor(s2, off);
    hn[row * 64 + lane] = f2bf(d * rsqrtf(s2 * (1.f / 64.f) + 1e-5f) * lg_[lane] + lb_[lane]);
}

// ---------------------------------------------------------------- BN apply + leaky -> bf16 (layer-1 GEMM input)
__global__ __launch_bounds__(256) void k_bn_bf16(
    const float* __restrict__ V, const float* __restrict__ stats,
    const float* __restrict__ bg, const float* __restrict__ bb,
    short* __restrict__ Hb)
{
    const int n = blockIdx.x, c = threadIdx.x;
    const float inv_n = 1.f / (float)NN;
    const float mu = stats[c] * inv_n;
    float var = stats[256 + c] * inv_n - mu * mu;
    var = fmaxf(var, 0.f);
    const float rsg = rsqrtf(var + 1e-5f) * bg[c];
    const float o = (V[(size_t)n * HC + c] - mu) * rsg + bb[c];
    Hb[(size_t)n * HC + c] = f2bf(leaky(o, NEG));
}

// ---------------------------------------------------------------- MFMA bf16 GEMM: [NN x D] @ [D x 512] -> X | Y (fp32)
template <int D>
__global__ __launch_bounds__(256) void k_gemm(
    const short* __restrict__ A, const short* __restrict__ Wt,
    float* __restrict__ X, float* __restrict__ Y)
{
    const int m0 = blockIdx.x * 16;
    const int w = threadIdx.x >> 6, lane = threadIdx.x & 63;
    const int n0 = w * 128;                     // waves 0,1 -> X; 2,3 -> Y
    const int r = lane & 15, q = lane >> 4;
    floatx4 acc[8];
    #pragma unroll
    for (int t = 0; t < 8; t++) acc[t] = (floatx4){0.f, 0.f, 0.f, 0.f};
    const short* Arow = A + (size_t)(m0 + r) * D + q * 8;
    const short* Brow = Wt + (size_t)(n0 + r) * D + q * 8;
    #pragma unroll
    for (int k0 = 0; k0 < D; k0 += 32) {
        const short8 a = *(const short8*)(Arow + k0);
        #pragma unroll
        for (int t = 0; t < 8; t++) {
            const short8 b = *(const short8*)(Brow + (size_t)t * 16 * D + k0);
            acc[t] = __builtin_amdgcn_mfma_f32_16x16x32_bf16(a, b, acc[t], 0, 0, 0);
        }
    }
    #pragma unroll
    for (int t = 0; t < 8; t++) {
        const int ncol = n0 + t * 16 + r;
        #pragma unroll
        for (int g2 = 0; g2 < 4; g2++) {
            const int row = m0 + q * 4 + g2;
            if (ncol < 256) X[(size_t)row * HC + ncol] = acc[t][g2];
            else            Y[(size_t)row * HC + (ncol - 256)] = acc[t][g2];
        }
    }
}

// ---------------------------------------------------------------- fused GATv2 (R5-measured-best shape): block = (graph, head, half)
__global__ __launch_bounds__(256, 4) void k_gat(
    const int* __restrict__ row_start, const int* __restrict__ row_cnt,
    const int* __restrict__ ssd, const float* __restrict__ ea_s,
    const float* __restrict__ We, const float* __restrict__ att,
    const float* __restrict__ bias,
    const float* __restrict__ X, const float* __restrict__ Y,
    float* __restrict__ V, float* __restrict__ stats)
{
    const int g = blockIdx.x >> 3;
    const int h = (blockIdx.x >> 1) & 3;
    const int half = blockIdx.x & 1;
    const int tid = threadIdx.x, w = tid >> 6, lane = tid & 63;
    const int nb = g * NROI, e0 = g * EPG, hc = h * 64;
    const int r0 = half * 58, r1 = r0 + 58;
    const int es = row_start[nb + r0];
    const int ee = (r1 < NROI) ? row_start[nb + r1] : e0 + EPG;

    __shared__ float Xs[NROI * XPAD];
    __shared__ float lg[EPB];
    __shared__ float inv_s[58];

    for (int r = w; r < NROI; r += 4)
        Xs[r * XPAD + lane] = X[(size_t)(nb + r) * HC + hc + lane];
    __syncthreads();

    // ---- phase A: logits, lane = edge (scalar reads, unroll 8 — measured-best)
    const int ne = ee - es;
    for (int i = tid; i < ne; i += 256) {
        const int e = es + i;
        const int sd = ssd[e];
        const int sl = sd & 0xffff, dl = sd >> 16;
        const float4 q = *(const float4*)&ea_s[(size_t)e * 8];
        const float q4 = ea_s[(size_t)e * 8 + 4];
        const float* yrow = &Y[(size_t)(nb + dl) * HC + hc];
        const int xb = sl * XPAD;
        float lacc = 0.f;
        #pragma unroll 8
        for (int c = 0; c < 64; c++) {
            float ep = q.x * We[0 * HC + hc + c];
            ep = fmaf(q.y, We[1 * HC + hc + c], ep);
            ep = fmaf(q.z, We[2 * HC + hc + c], ep);
            ep = fmaf(q.w, We[3 * HC + hc + c], ep);
            ep = fmaf(q4, We[4 * HC + hc + c], ep);
            const float z = Xs[xb + c] + yrow[c] + ep;
            lacc = fmaf(att[hc + c], leaky(z, NEGA), lacc);
        }
        lg[i] = lacc;
    }
    __syncthreads();

    // ---- phase B: per-row max / exp / sum; store reciprocal
    for (int r = r0 + w; r < r1; r += 4) {
        const int stl = row_start[nb + r] - es;
        const int cnt = row_cnt[nb + r];
        float m = -INFINITY;
        for (int j = lane; j < cnt; j += 64) m = fmaxf(m, lg[stl + j]);
        #pragma unroll
        for (int off = 32; off; off >>= 1) m = fmaxf(m, __shfl_xor(m, off));
        float s = 0.f;
        for (int j = lane; j < cnt; j += 64) {
            const float e_ = __expf(lg[stl + j] - m);
            lg[stl + j] = e_;
            s += e_;
        }
        #pragma unroll
        for (int off = 32; off; off >>= 1) s += __shfl_xor(s, off);
        if (lane == 0) inv_s[r - r0] = 1.f / (s + 1e-16f);
    }
    __syncthreads();

    // ---- phase C: numerator (wave per row, lane = channel) + BN partials
    float ps = 0.f, ps2 = 0.f;
    const float bb = bias[hc + lane];
    for (int r = r0 + w; r < r1; r += 4) {
        const int st = row_start[nb + r];
        const int cnt = row_cnt[nb + r];
        const int stl = st - es;
        float a0 = 0.f, a1 = 0.f, a2 = 0.f, a3 = 0.f;
        int j = 0;
        for (; j + 4 <= cnt; j += 4) {
            const int s0 = ssd[st + j] & 0xffff, s1 = ssd[st + j + 1] & 0xffff,
                      s2 = ssd[st + j + 2] & 0xffff, s3 = ssd[st + j + 3] & 0xffff;
            a0 = fmaf(Xs[s0 * XPAD + lane], lg[stl + j], a0);
            a1 = fmaf(Xs[s1 * XPAD + lane], lg[stl + j + 1], a1);
            a2 = fmaf(Xs[s2 * XPAD + lane], lg[stl + j + 2], a2);
            a3 = fmaf(Xs[s3 * XPAD + lane], lg[stl + j + 3], a3);
        }
        for (; j < cnt; j++)
            a0 = fmaf(Xs[(ssd[st + j] & 0xffff) * XPAD + lane], lg[stl + j], a0);
        const float vv = ((a0 + a1) + (a2 + a3)) * inv_s[r - r0] + bb;
        V[(size_t)(nb + r) * HC + hc + lane] = vv;
        ps += vv;
        ps2 += vv * vv;
    }
    __syncthreads();                 // lg free; reuse as reduction buffer
    lg[tid] = ps;
    lg[256 + tid] = ps2;
    __syncthreads();
    if (tid < 64) {
        float s1 = 0.f, s2 = 0.f;
        #pragma unroll
        for (int w2 = 0; w2 < 4; w2++) {
            s1 += lg[w2 * 64 + tid];
            s2 += lg[256 + w2 * 64 + tid];
        }
        atomicAdd(&stats[hc + tid], s1);
        atomicAdd(&stats[256 + hc + tid], s2);
    }
}

// ---------------------------------------------------------------- BN + leaky + mean-pool + classifier
__global__ __launch_bounds__(256) void k_pool_fc(
    const float* __restrict__ V, const float* __restrict__ stats,
    const float* __restrict__ bg, const float* __restrict__ bb,
    const float* __restrict__ fW, const float* __restrict__ fb,
    float* __restrict__ out)
{
    const int g = blockIdx.x, c = threadIdx.x;
    const float inv_n = 1.f / (float)NN;
    const float mu = stats[c] * inv_n;
    float var = stats[256 + c] * inv_n - mu * mu;
    var = fmaxf(var, 0.f);
    const float rsg = rsqrtf(var + 1e-5f) * bg[c];
    const float bbc = bb[c];
    float s = 0.f;
    for (int r = 0; r < NROI; r++) {
        const float vv = (V[(size_t)(g * NROI + r) * HC + c] - mu) * rsg + bbc;
        s += leaky(vv, NEG);
    }
    s *= (1.f / (float)NROI);
    __shared__ float red[256];
    for (int o = 0; o < 2; o++) {
        red[c] = s * fW[c * 2 + o];
        __syncthreads();
        for (int off = 128; off; off >>= 1) {
            if (c < off) red[c] += red[c + off];
            __syncthreads();
        }
        if (c == 0) out[g * 2 + o] = red[0] + fb[o];
        __syncthreads();
    }
}

extern "C" void kernel_launch(void* const* d_in, const int* in_sizes, int n_in,
                              void* d_out, int out_size, void* d_ws, size_t ws_size,
                              hipStream_t stream) {
    const float* x         = (const float*)d_in[0];
    const int*   edge_idx  = (const int*)d_in[1];
    const float* edge_attr = (const float*)d_in[2];
    const int*   node_grp  = (const int*)d_in[4];
    const float* group_emb = (const float*)d_in[5];
    const float* W_embed   = (const float*)d_in[6];
    const float* b_embed   = (const float*)d_in[7];
    const float* We_enc    = (const float*)d_in[8];
    const float* be_enc    = (const float*)d_in[9];
    const float* W1        = (const float*)d_in[10];
    const float* b1        = (const float*)d_in[11];
    const float* W2        = (const float*)d_in[12];
    const float* b2        = (const float*)d_in[13];
    const float* ln_g      = (const float*)d_in[14];
    const float* ln_b      = (const float*)d_in[15];
    const float* l0_Wl     = (const float*)d_in[16];
    const float* l0_Wr     = (const float*)d_in[17];
    const float* l0_We     = (const float*)d_in[18];
    const float* l0_att    = (const float*)d_in[19];
    const float* l0_b      = (const float*)d_in[20];
    const float* l0_bn_g   = (const float*)d_in[21];
    const float* l0_bn_b   = (const float*)d_in[22];
    const float* l1_Wl     = (const float*)d_in[23];
    const float* l1_Wr     = (const float*)d_in[24];
    const float* l1_We     = (const float*)d_in[25];
    const float* l1_att    = (const float*)d_in[26];
    const float* l1_b      = (const float*)d_in[27];
    const float* l1_bn_g   = (const float*)d_in[28];
    const float* l1_bn_b   = (const float*)d_in[29];
    const float* fc2_W     = (const float*)d_in[30];
    const float* fc2_b     = (const float*)d_in[31];

    const int* src = edge_idx;
    const int* dst = edge_idx + NE;

    float* ws     = (float*)d_ws;
    float* h0     = ws;                       // 64*NN f32
    float* X      = h0 + (size_t)64 * NN;     // 256*NN f32
    float* Y      = X + (size_t)HC * NN;      // 256*NN f32
    float* V      = Y + (size_t)HC * NN;      // 256*NN f32
    float* stats0 = V + (size_t)HC * NN;      // 512
    float* stats1 = stats0 + 512;             // 512
    float* ea_s   = stats1 + 512;             // 8*NE f32
    int* row_start = (int*)(ea_s + (size_t)8 * NE);  // NN
    int* row_cnt   = row_start + NN;                 // NN
    int* ssd       = row_cnt + NN;                   // NE
    short* hn_b    = (short*)(ssd + NE);             // 64*NN bf16
    short* Hb1     = hn_b + (size_t)64 * NN;         // 256*NN bf16
    short* Wt0     = Hb1 + (size_t)HC * NN;          // 512*64 bf16
    short* Wt1     = Wt0 + 512 * 64;                 // 512*256 bf16

    float* out = (float*)d_out;

    hipMemsetAsync(stats0, 0, 1024 * sizeof(float), stream);  // stats0 + stats1
    k_embed<<<NN / 4, 256, 0, stream>>>(x, node_grp, group_emb, W_embed, b_embed, h0);
    k_csr<<<NGRAPH, 256, 0, stream>>>(src, dst, edge_attr, row_start, row_cnt, ssd, ea_s);
    k_prep_w<<<1024, 64, 0, stream>>>(l0_Wl, l0_Wr, l1_Wl, l1_Wr, Wt0, Wt1);
    k_gine_mlp_ln<<<NN / 4, 256, 0, stream>>>(h0, row_start, row_cnt, ssd, ea_s,
                                              We_enc, be_enc, W1, b1, W2, b2, ln_g, ln_b, hn_b);

    // GAT layer 0
    k_gemm<64><<<NN / 16, 256, 0, stream>>>(hn_b, Wt0, X, Y);
    k_gat<<<NGRAPH * 8, 256, 0, stream>>>(row_start, row_cnt, ssd, ea_s,
                                          l0_We, l0_att, l0_b, X, Y, V, stats0);

    // GAT layer 1
    k_bn_bf16<<<NN, 256, 0, stream>>>(V, stats0, l0_bn_g, l0_bn_b, Hb1);
    k_gemm<256><<<NN / 16, 256, 0, stream>>>(Hb1, Wt1, X, Y);
    k_gat<<<NGRAPH * 8, 256, 0, stream>>>(row_start, row_cnt, ssd, ea_s,
                                          l1_We, l1_att, l1_b, X, Y, V, stats1);

    // BN+leaky of layer-1 output fused into pooling
    k_pool_fc<<<NGRAPH, 256, 0, stream>>>(V, stats1, l1_bn_g, l1_bn_b, fc2_W, fc2_b, out);
}

// Round 8
// 451.911 us; speedup vs baseline: 1.1917x; 1.0049x over previous
//
#include <hip/hip_runtime.h>
#include <hip/hip_bf16.h>

#define NN     14848      // nodes
#define NE     475136     // edges
#define NROI   116        // nodes per graph
#define NGRAPH 128        // graphs
#define EPG    3712       // edges per graph (116*32)
#define HID    64
#define HC     256
#define NEG    0.01f
#define NEGA   0.2f
#define EPB    2304       // max edges per half-graph block (mean 1856)
#define XPAD   65         // Xs row stride (R5/R7-measured best)

typedef __attribute__((ext_vector_type(8))) short short8;
typedef __attribute__((ext_vector_type(4))) float floatx4;

// leaky(x) = max(x, s*x) for 0<s<1 — 2 VALU, no branch
__device__ __forceinline__ float leaky(float x, float s) { return fmaxf(x, s * x); }

// round-to-nearest-even float -> bf16 bits
__device__ __forceinline__ short f2bf(float f) {
    unsigned u = __float_as_uint(f);
    unsigned r = (u + 0x7fffu + ((u >> 16) & 1u)) >> 16;
    return (short)r;
}

// ---------------------------------------------------------------- embed (4 nodes/block)
__global__ __launch_bounds__(256) void k_embed(
    const float* __restrict__ x, const int* __restrict__ ng,
    const float* __restrict__ gemb, const float* __restrict__ W,
    const float* __restrict__ b, float* __restrict__ h0)
{
    const int w = threadIdx.x >> 6, c = threadIdx.x & 63;
    const int n = blockIdx.x * 4 + w;
    __shared__ float in[4][132];
    for (int k = c; k < NROI; k += 64) in[w][k] = x[n * NROI + k];
    if (c < 16) in[w][NROI + c] = gemb[ng[n] * 16 + c];
    __syncthreads();
    float acc = b[c];
    #pragma unroll 4
    for (int k = 0; k < 132; k++) acc = fmaf(in[w][k], W[k * 64 + c], acc);
    h0[n * 64 + c] = leaky(acc, NEG);
}

// ---------------------------------------------------------------- CSR build (counting sort by dst, per graph)
// blocks 0/1 also zero the BN stats buffers (replaces a memset dispatch)
__global__ __launch_bounds__(256) void k_csr(
    const int* __restrict__ src, const int* __restrict__ dst,
    const float* __restrict__ ea,
    int* __restrict__ row_start, int* __restrict__ row_cnt,
    int* __restrict__ ssd, float* __restrict__ ea_s,
    float* __restrict__ stats01)
{
    const int g = blockIdx.x, tid = threadIdx.x;
    if (g < 2) {
        for (int i = tid; i < 512; i += 256) stats01[g * 512 + i] = 0.f;
    }
    const int e0 = g * EPG, nb = g * NROI;
    __shared__ int cnt[NROI], start[NROI], cur[NROI];
    if (tid < NROI) cnt[tid] = 0;
    __syncthreads();
    for (int i = tid; i < EPG; i += 256) atomicAdd(&cnt[dst[e0 + i] - nb], 1);
    __syncthreads();
    if (tid == 0) {
        int s = 0;
        for (int r = 0; r < NROI; r++) { start[r] = s; s += cnt[r]; }
    }
    __syncthreads();
    if (tid < NROI) {
        row_start[nb + tid] = e0 + start[tid];
        row_cnt[nb + tid] = cnt[tid];
        cur[tid] = start[tid];
    }
    __syncthreads();
    for (int i = tid; i < EPG; i += 256) {
        const int e = e0 + i, dl = dst[e] - nb;
        const int pos = atomicAdd(&cur[dl], 1);
        const int gi = e0 + pos;
        ssd[gi] = (src[e] - nb) | (dl << 16);
        const float4 q = make_float4(ea[e * 5], ea[e * 5 + 1], ea[e * 5 + 2], ea[e * 5 + 3]);
        *(float4*)&ea_s[(size_t)gi * 8] = q;
        ea_s[(size_t)gi * 8 + 4] = ea[e * 5 + 4];
    }
}

// ---------------------------------------------------------------- weight prep (both layers, one launch)
__global__ __launch_bounds__(64) void k_prep_w(
    const float* __restrict__ Wl0, const float* __restrict__ Wr0,
    const float* __restrict__ Wl1, const float* __restrict__ Wr1,
    short* __restrict__ Wt0, short* __restrict__ Wt1)
{
    if (blockIdx.x < 512) {
        const int n = blockIdx.x;
        for (int k = threadIdx.x; k < 64; k += 64) {
            const float v = (n < 256) ? Wl0[k * 256 + n] : Wr0[k * 256 + (n - 256)];
            Wt0[(size_t)n * 64 + k] = f2bf(v);
        }
    } else {
        const int n = blockIdx.x - 512;
        for (int k = threadIdx.x; k < 256; k += 64) {
            const float v = (n < 256) ? Wl1[k * 256 + n] : Wr1[k * 256 + (n - 256)];
            Wt1[(size_t)n * 256 + k] = f2bf(v);
        }
    }
}

// ---------------------------------------------------------------- GINE (CSR, per-row wave) fused with MLP + LayerNorm -> bf16
__global__ __launch_bounds__(256) void k_gine_mlp_ln(
    const float* __restrict__ h0, const int* __restrict__ row_start,
    const int* __restrict__ row_cnt, const int* __restrict__ ssd,
    const float* __restrict__ ea_s,
    const float* __restrict__ We, const float* __restrict__ be,
    const float* __restrict__ W1, const float* __restrict__ b1,
    const float* __restrict__ W2, const float* __restrict__ b2,
    const float* __restrict__ lg_, const float* __restrict__ lb_,
    short* __restrict__ hn)
{
    const int tid = threadIdx.x, w = tid >> 6, lane = tid & 63;
    const int row = blockIdx.x * 4 + w;
    const int nb = (row / NROI) * NROI;
    const int st = row_start[row], cnt = row_cnt[row];
    const float w0 = We[lane], w1 = We[64 + lane], w2 = We[128 + lane],
                w3 = We[192 + lane], w4 = We[256 + lane];
    const float bec = be[lane];
    float g0 = 0.f, g1 = 0.f;
    int j = 0;
    for (; j + 2 <= cnt; j += 2) {
        const int ia = st + j, ib = st + j + 1;
        const int sa = nb + (ssd[ia] & 0xffff), sb = nb + (ssd[ib] & 0xffff);
        const float4 qa = *(const float4*)&ea_s[(size_t)ia * 8];
        const float qa4 = ea_s[(size_t)ia * 8 + 4];
        const float4 qb = *(const float4*)&ea_s[(size_t)ib * 8];
        const float qb4 = ea_s[(size_t)ib * 8 + 4];
        float ea_ = bec, eb_ = bec;
        ea_ = fmaf(qa.x, w0, ea_); eb_ = fmaf(qb.x, w0, eb_);
        ea_ = fmaf(qa.y, w1, ea_); eb_ = fmaf(qb.y, w1, eb_);
        ea_ = fmaf(qa.z, w2, ea_); eb_ = fmaf(qb.z, w2, eb_);
        ea_ = fmaf(qa.w, w3, ea_); eb_ = fmaf(qb.w, w3, eb_);
        ea_ = fmaf(qa4, w4, ea_);  eb_ = fmaf(qb4, w4, eb_);
        g0 += fmaxf(h0[sa * 64 + lane] + leaky(ea_, NEG), 0.f);
        g1 += fmaxf(h0[sb * 64 + lane] + leaky(eb_, NEG), 0.f);
    }
    for (; j < cnt; j++) {
        const int idx = st + j;
        const int s = nb + (ssd[idx] & 0xffff);
        const float4 q = *(const float4*)&ea_s[(size_t)idx * 8];
        const float q4 = ea_s[(size_t)idx * 8 + 4];
        float em = bec;
        em = fmaf(q.x, w0, em); em = fmaf(q.y, w1, em); em = fmaf(q.z, w2, em);
        em = fmaf(q.w, w3, em); em = fmaf(q4, w4, em);
        g0 += fmaxf(h0[s * 64 + lane] + leaky(em, NEG), 0.f);
    }
    const float aggv = g0 + g1;
    __shared__ float v[4][64], t[4][64];
    v[w][lane] = h0[row * 64 + lane] + aggv;
    __syncthreads();
    float a = b1[lane];
    #pragma unroll 8
    for (int k = 0; k < 64; k++) a = fmaf(v[w][k], W1[k * 64 + lane], a);
    t[w][lane] = leaky(a, NEG);
    __syncthreads();
    float o = b2[lane];
    #pragma unroll 8
    for (int k = 0; k < 64; k++) o = fmaf(t[w][k], W2[k * 64 + lane], o);
    o = leaky(o, NEG);
    float s = o;
    #pragma unroll
    for (int off = 32; off; off >>= 1) s += __shfl_xor(s, off);
    const float mu = s * (1.f / 64.f);
    const float d = o - mu;
    float s2 = d * d;
    #pragma unroll
    for (int off = 32; off; off >>= 1) s2 += __shfl_xor(s2, off);
    hn[row * 64 + lane] = f2bf(d * rsqrtf(s2 * (1.f / 64.f) + 1e-5f) * lg_[lane] + lb_[lane]);
}

// ---------------------------------------------------------------- MFMA bf16 GEMM: [NN x D] @ [D x 512] -> X | Y (fp32)
// BN=true: A comes from fp32 Vin with fused BatchNorm+leaky+bf16-cast (per-channel
// scale/shift precomputed in LDS; each Vin element is read exactly once per block).
template <int D, bool BN>
__global__ __launch_bounds__(256) void k_gemm(
    const short* __restrict__ A, const float* __restrict__ Vin,
    const float* __restrict__ stats, const float* __restrict__ bn_g,
    const float* __restrict__ bn_b,
    const short* __restrict__ Wt,
    float* __restrict__ X, float* __restrict__ Y)
{
    const int m0 = blockIdx.x * 16;
    const int w = threadIdx.x >> 6, lane = threadIdx.x & 63;
    const int n0 = w * 128;                     // waves 0,1 -> X; 2,3 -> Y
    const int r = lane & 15, q = lane >> 4;
    __shared__ float sc_s[256], sh_s[256];
    if constexpr (BN) {
        const int c = threadIdx.x;
        const float inv_n = 1.f / (float)NN;
        const float mu = stats[c] * inv_n;
        float var = stats[256 + c] * inv_n - mu * mu;
        var = fmaxf(var, 0.f);
        const float rsg = rsqrtf(var + 1e-5f) * bn_g[c];
        sc_s[c] = rsg;
        sh_s[c] = bn_b[c] - mu * rsg;
        __syncthreads();
    }
    floatx4 acc[8];
    #pragma unroll
    for (int t = 0; t < 8; t++) acc[t] = (floatx4){0.f, 0.f, 0.f, 0.f};
    const short* Arow = A + (size_t)(m0 + r) * D + q * 8;
    const float* Vrow = Vin + (size_t)(m0 + r) * D + q * 8;
    const short* Brow = Wt + (size_t)(n0 + r) * D + q * 8;
    #pragma unroll
    for (int k0 = 0; k0 < D; k0 += 32) {
        short8 a;
        if constexpr (BN) {
            const float4 v0 = *(const float4*)(Vrow + k0);
            const float4 v1 = *(const float4*)(Vrow + k0 + 4);
            const int cb = q * 8 + k0;
            a[0] = f2bf(leaky(fmaf(v0.x, sc_s[cb + 0], sh_s[cb + 0]), NEG));
            a[1] = f2bf(leaky(fmaf(v0.y, sc_s[cb + 1], sh_s[cb + 1]), NEG));
            a[2] = f2bf(leaky(fmaf(v0.z, sc_s[cb + 2], sh_s[cb + 2]), NEG));
            a[3] = f2bf(leaky(fmaf(v0.w, sc_s[cb + 3], sh_s[cb + 3]), NEG));
            a[4] = f2bf(leaky(fmaf(v1.x, sc_s[cb + 4], sh_s[cb + 4]), NEG));
            a[5] = f2bf(leaky(fmaf(v1.y, sc_s[cb + 5], sh_s[cb + 5]), NEG));
            a[6] = f2bf(leaky(fmaf(v1.z, sc_s[cb + 6], sh_s[cb + 6]), NEG));
            a[7] = f2bf(leaky(fmaf(v1.w, sc_s[cb + 7], sh_s[cb + 7]), NEG));
        } else {
            a = *(const short8*)(Arow + k0);
        }
        #pragma unroll
        for (int t = 0; t < 8; t++) {
            const short8 b = *(const short8*)(Brow + (size_t)t * 16 * D + k0);
            acc[t] = __builtin_amdgcn_mfma_f32_16x16x32_bf16(a, b, acc[t], 0, 0, 0);
        }
    }
    #pragma unroll
    for (int t = 0; t < 8; t++) {
        const int ncol = n0 + t * 16 + r;
        #pragma unroll
        for (int g2 = 0; g2 < 4; g2++) {
            const int row = m0 + q * 4 + g2;
            if (ncol < 256) X[(size_t)row * HC + ncol] = acc[t][g2];
            else            Y[(size_t)row * HC + (ncol - 256)] = acc[t][g2];
        }
    }
}

// ---------------------------------------------------------------- fused GATv2 (R7 shape, paired loads): block = (graph, head, half)
__global__ __launch_bounds__(256, 4) void k_gat(
    const int* __restrict__ row_start, const int* __restrict__ row_cnt,
    const int* __restrict__ ssd, const float* __restrict__ ea_s,
    const float* __restrict__ We, const float* __restrict__ att,
    const float* __restrict__ bias,
    const float* __restrict__ X, const float* __restrict__ Y,
    float* __restrict__ V, float* __restrict__ stats)
{
    const int g = blockIdx.x >> 3;
    const int h = (blockIdx.x >> 1) & 3;
    const int half = blockIdx.x & 1;
    const int tid = threadIdx.x, w = tid >> 6, lane = tid & 63;
    const int nb = g * NROI, e0 = g * EPG, hc = h * 64;
    const int r0 = half * 58, r1 = r0 + 58;
    const int es = row_start[nb + r0];
    const int ee = (r1 < NROI) ? row_start[nb + r1] : e0 + EPG;

    __shared__ float Xs[NROI * XPAD];
    __shared__ float lg[EPB];
    __shared__ float inv_s[58];

    for (int r = w; r < NROI; r += 4)
        Xs[r * XPAD + lane] = X[(size_t)(nb + r) * HC + hc + lane];
    __syncthreads();

    // ---- phase A: logits, lane = edge (paired LDS/VMEM reads: ds_read2_b32 + dwordx2)
    const int ne = ee - es;
    for (int i = tid; i < ne; i += 256) {
        const int e = es + i;
        const int sd = ssd[e];
        const int sl = sd & 0xffff, dl = sd >> 16;
        const float4 q = *(const float4*)&ea_s[(size_t)e * 8];
        const float q4 = ea_s[(size_t)e * 8 + 4];
        const float* yrow = &Y[(size_t)(nb + dl) * HC + hc];
        const int xb = sl * XPAD;
        float l0 = 0.f, l1 = 0.f;
        #pragma unroll 8
        for (int c = 0; c < 64; c += 2) {
            const float2 y2 = *(const float2*)(yrow + c);   // 8B-aligned (even c)
            const float xs0 = Xs[xb + c], xs1 = Xs[xb + c + 1];  // fuses to ds_read2_b32
            float ep0 = q.x * We[0 * HC + hc + c];
            ep0 = fmaf(q.y, We[1 * HC + hc + c], ep0);
            ep0 = fmaf(q.z, We[2 * HC + hc + c], ep0);
            ep0 = fmaf(q.w, We[3 * HC + hc + c], ep0);
            ep0 = fmaf(q4, We[4 * HC + hc + c], ep0);
            float ep1 = q.x * We[0 * HC + hc + c + 1];
            ep1 = fmaf(q.y, We[1 * HC + hc + c + 1], ep1);
            ep1 = fmaf(q.z, We[2 * HC + hc + c + 1], ep1);
            ep1 = fmaf(q.w, We[3 * HC + hc + c + 1], ep1);
            ep1 = fmaf(q4, We[4 * HC + hc + c + 1], ep1);
            const float z0 = xs0 + y2.x + ep0;
            const float z1 = xs1 + y2.y + ep1;
            l0 = fmaf(att[hc + c], leaky(z0, NEGA), l0);
            l1 = fmaf(att[hc + c + 1], leaky(z1, NEGA), l1);
        }
        lg[i] = l0 + l1;
    }
    __syncthreads();

    // ---- phase B: per-row max / exp / sum; store reciprocal
    for (int r = r0 + w; r < r1; r += 4) {
        const int stl = row_start[nb + r] - es;
        const int cnt = row_cnt[nb + r];
        float m = -INFINITY;
        for (int j = lane; j < cnt; j += 64) m = fmaxf(m, lg[stl + j]);
        #pragma unroll
        for (int off = 32; off; off >>= 1) m = fmaxf(m, __shfl_xor(m, off));
        float s = 0.f;
        for (int j = lane; j < cnt; j += 64) {
            const float e_ = __expf(lg[stl + j] - m);
            lg[stl + j] = e_;
            s += e_;
        }
        #pragma unroll
        for (int off = 32; off; off >>= 1) s += __shfl_xor(s, off);
        if (lane == 0) inv_s[r - r0] = 1.f / (s + 1e-16f);
    }
    __syncthreads();

    // ---- phase C: numerator (wave per row, lane = channel) + BN partials
    float ps = 0.f, ps2 = 0.f;
    const float bb = bias[hc + lane];
    for (int r = r0 + w; r < r1; r += 4) {
        const int st = row_start[nb + r];
        const int cnt = row_cnt[nb + r];
        const int stl = st - es;
        float a0 = 0.f, a1 = 0.f, a2 = 0.f, a3 = 0.f;
        int j = 0;
        for (; j + 4 <= cnt; j += 4) {
            const int s0 = ssd[st + j] & 0xffff, s1 = ssd[st + j + 1] & 0xffff,
                      s2 = ssd[st + j + 2] & 0xffff, s3 = ssd[st + j + 3] & 0xffff;
            a0 = fmaf(Xs[s0 * XPAD + lane], lg[stl + j], a0);
            a1 = fmaf(Xs[s1 * XPAD + lane], lg[stl + j + 1], a1);
            a2 = fmaf(Xs[s2 * XPAD + lane], lg[stl + j + 2], a2);
            a3 = fmaf(Xs[s3 * XPAD + lane], lg[stl + j + 3], a3);
        }
        for (; j < cnt; j++)
            a0 = fmaf(Xs[(ssd[st + j] & 0xffff) * XPAD + lane], lg[stl + j], a0);
        const float vv = ((a0 + a1) + (a2 + a3)) * inv_s[r - r0] + bb;
        V[(size_t)(nb + r) * HC + hc + lane] = vv;
        ps += vv;
        ps2 += vv * vv;
    }
    __syncthreads();                 // lg free; reuse as reduction buffer
    lg[tid] = ps;
    lg[256 + tid] = ps2;
    __syncthreads();
    if (tid < 64) {
        float s1 = 0.f, s2 = 0.f;
        #pragma unroll
        for (int w2 = 0; w2 < 4; w2++) {
            s1 += lg[w2 * 64 + tid];
            s2 += lg[256 + w2 * 64 + tid];
        }
        atomicAdd(&stats[hc + tid], s1);
        atomicAdd(&stats[256 + hc + tid], s2);
    }
}

// ---------------------------------------------------------------- BN + leaky + mean-pool + classifier
__global__ __launch_bounds__(256) void k_pool_fc(
    const float* __restrict__ V, const float* __restrict__ stats,
    const float* __restrict__ bg, const float* __restrict__ bb,
    const float* __restrict__ fW, const float* __restrict__ fb,
    float* __restrict__ out)
{
    const int g = blockIdx.x, c = threadIdx.x;
    const float inv_n = 1.f / (float)NN;
    const float mu = stats[c] * inv_n;
    float var = stats[256 + c] * inv_n - mu * mu;
    var = fmaxf(var, 0.f);
    const float rsg = rsqrtf(var + 1e-5f) * bg[c];
    const float bbc = bb[c];
    float s = 0.f;
    for (int r = 0; r < NROI; r++) {
        const float vv = (V[(size_t)(g * NROI + r) * HC + c] - mu) * rsg + bbc;
        s += leaky(vv, NEG);
    }
    s *= (1.f / (float)NROI);
    __shared__ float red[256];
    for (int o = 0; o < 2; o++) {
        red[c] = s * fW[c * 2 + o];
        __syncthreads();
        for (int off = 128; off; off >>= 1) {
            if (c < off) red[c] += red[c + off];
            __syncthreads();
        }
        if (c == 0) out[g * 2 + o] = red[0] + fb[o];
        __syncthreads();
    }
}

extern "C" void kernel_launch(void* const* d_in, const int* in_sizes, int n_in,
                              void* d_out, int out_size, void* d_ws, size_t ws_size,
                              hipStream_t stream) {
    const float* x         = (const float*)d_in[0];
    const int*   edge_idx  = (const int*)d_in[1];
    const float* edge_attr = (const float*)d_in[2];
    const int*   node_grp  = (const int*)d_in[4];
    const float* group_emb = (const float*)d_in[5];
    const float* W_embed   = (const float*)d_in[6];
    const float* b_embed   = (const float*)d_in[7];
    const float* We_enc    = (const float*)d_in[8];
    const float* be_enc    = (const float*)d_in[9];
    const float* W1        = (const float*)d_in[10];
    const float* b1        = (const float*)d_in[11];
    const float* W2        = (const float*)d_in[12];
    const float* b2        = (const float*)d_in[13];
    const float* ln_g      = (const float*)d_in[14];
    const float* ln_b      = (const float*)d_in[15];
    const float* l0_Wl     = (const float*)d_in[16];
    const float* l0_Wr     = (const float*)d_in[17];
    const float* l0_We     = (const float*)d_in[18];
    const float* l0_att    = (const float*)d_in[19];
    const float* l0_b      = (const float*)d_in[20];
    const float* l0_bn_g   = (const float*)d_in[21];
    const float* l0_bn_b   = (const float*)d_in[22];
    const float* l1_Wl     = (const float*)d_in[23];
    const float* l1_Wr     = (const float*)d_in[24];
    const float* l1_We     = (const float*)d_in[25];
    const float* l1_att    = (const float*)d_in[26];
    const float* l1_b      = (const float*)d_in[27];
    const float* l1_bn_g   = (const float*)d_in[28];
    const float* l1_bn_b   = (const float*)d_in[29];
    const float* fc2_W     = (const float*)d_in[30];
    const float* fc2_b     = (const float*)d_in[31];

    const int* src = edge_idx;
    const int* dst = edge_idx + NE;

    float* ws     = (float*)d_ws;
    float* h0     = ws;                       // 64*NN f32
    float* X      = h0 + (size_t)64 * NN;     // 256*NN f32
    float* Y      = X + (size_t)HC * NN;      // 256*NN f32
    float* V      = Y + (size_t)HC * NN;      // 256*NN f32
    float* stats0 = V + (size_t)HC * NN;      // 512
    float* stats1 = stats0 + 512;             // 512
    float* ea_s   = stats1 + 512;             // 8*NE f32
    int* row_start = (int*)(ea_s + (size_t)8 * NE);  // NN
    int* row_cnt   = row_start + NN;                 // NN
    int* ssd       = row_cnt + NN;                   // NE
    short* hn_b    = (short*)(ssd + NE);             // 64*NN bf16
    short* Wt0     = hn_b + (size_t)64 * NN;         // 512*64 bf16
    short* Wt1     = Wt0 + 512 * 64;                 // 512*256 bf16

    float* out = (float*)d_out;

    k_embed<<<NN / 4, 256, 0, stream>>>(x, node_grp, group_emb, W_embed, b_embed, h0);
    k_csr<<<NGRAPH, 256, 0, stream>>>(src, dst, edge_attr, row_start, row_cnt, ssd, ea_s, stats0);
    k_prep_w<<<1024, 64, 0, stream>>>(l0_Wl, l0_Wr, l1_Wl, l1_Wr, Wt0, Wt1);
    k_gine_mlp_ln<<<NN / 4, 256, 0, stream>>>(h0, row_start, row_cnt, ssd, ea_s,
                                              We_enc, be_enc, W1, b1, W2, b2, ln_g, ln_b, hn_b);

    // GAT layer 0
    k_gemm<64, false><<<NN / 16, 256, 0, stream>>>(hn_b, nullptr, nullptr, nullptr, nullptr,
                                                   Wt0, X, Y);
    k_gat<<<NGRAPH * 8, 256, 0, stream>>>(row_start, row_cnt, ssd, ea_s,
                                          l0_We, l0_att, l0_b, X, Y, V, stats0);

    // GAT layer 1 (BN+leaky+bf16 of layer-0 output fused into GEMM A-load)
    k_gemm<256, true><<<NN / 16, 256, 0, stream>>>(nullptr, V, stats0, l0_bn_g, l0_bn_b,
                                                   Wt1, X, Y);
    k_gat<<<NGRAPH * 8, 256, 0, stream>>>(row_start, row_cnt, ssd, ea_s,
                                          l1_We, l1_att, l1_b, X, Y, V, stats1);

    // BN+leaky of layer-1 output fused into pooling
    k_pool_fc<<<NGRAPH, 256, 0, stream>>>(V, stats1, l1_bn_g, l1_bn_b, fc2_W, fc2_b, out);
}

// Round 9
// 430.725 us; speedup vs baseline: 1.2504x; 1.0492x over previous
//
#include <hip/hip_runtime.h>
#include <hip/hip_bf16.h>

#define NN     14848      // nodes
#define NE     475136     // edges
#define NROI   116        // nodes per graph
#define NGRAPH 128        // graphs
#define EPG    3712       // edges per graph (116*32)
#define HID    64
#define HC     256
#define NEG    0.01f
#define NEGA   0.2f
#define EPB    2304       // max edges per half-graph block (mean 1856)
#define XPAD   65         // Xs row stride (R5/R7-measured best)

typedef __attribute__((ext_vector_type(8))) short short8;
typedef __attribute__((ext_vector_type(4))) float floatx4;
typedef __attribute__((ext_vector_type(2))) float floatx2;

// leaky(x) = max(x, s*x) for 0<s<1 — 2 VALU, no branch
__device__ __forceinline__ float leaky(float x, float s) { return fmaxf(x, s * x); }

// round-to-nearest-even float -> bf16 bits
__device__ __forceinline__ short f2bf(float f) {
    unsigned u = __float_as_uint(f);
    unsigned r = (u + 0x7fffu + ((u >> 16) & 1u)) >> 16;
    return (short)r;
}

// ---------------------------------------------------------------- front: embed + CSR + weight prep (independent; one dispatch)
// blocks [0, NN/4)           : embed, 4 nodes/block
// blocks [NN/4, NN/4+128)    : CSR counting sort (blocks 0/1 also zero stats)
// blocks [NN/4+128, +1024)   : weight transpose/bf16 (512 for Wt0, 512 for Wt1)
__global__ __launch_bounds__(256) void k_front(
    const float* __restrict__ x, const int* __restrict__ ng,
    const float* __restrict__ gemb, const float* __restrict__ W,
    const float* __restrict__ b, float* __restrict__ h0,
    const int* __restrict__ src, const int* __restrict__ dst,
    const float* __restrict__ ea,
    int* __restrict__ row_start, int* __restrict__ row_cnt,
    int* __restrict__ ssd, float* __restrict__ ea_s,
    float* __restrict__ stats01,
    const float* __restrict__ Wl0, const float* __restrict__ Wr0,
    const float* __restrict__ Wl1, const float* __restrict__ Wr1,
    short* __restrict__ Wt0, short* __restrict__ Wt1)
{
    const int tid = threadIdx.x;
    if (blockIdx.x < NN / 4) {
        // ---- embed
        const int w = tid >> 6, c = tid & 63;
        const int n = blockIdx.x * 4 + w;
        __shared__ float in[4][132];
        for (int k = c; k < NROI; k += 64) in[w][k] = x[n * NROI + k];
        if (c < 16) in[w][NROI + c] = gemb[ng[n] * 16 + c];
        __syncthreads();
        float acc = b[c];
        #pragma unroll 4
        for (int k = 0; k < 132; k++) acc = fmaf(in[w][k], W[k * 64 + c], acc);
        h0[n * 64 + c] = leaky(acc, NEG);
    } else if (blockIdx.x < NN / 4 + NGRAPH) {
        // ---- CSR
        const int g = blockIdx.x - NN / 4;
        if (g < 2) {
            for (int i = tid; i < 512; i += 256) stats01[g * 512 + i] = 0.f;
        }
        const int e0 = g * EPG, nb = g * NROI;
        __shared__ int cnt[NROI], start[NROI], cur[NROI];
        if (tid < NROI) cnt[tid] = 0;
        __syncthreads();
        for (int i = tid; i < EPG; i += 256) atomicAdd(&cnt[dst[e0 + i] - nb], 1);
        __syncthreads();
        if (tid == 0) {
            int s = 0;
            for (int r = 0; r < NROI; r++) { start[r] = s; s += cnt[r]; }
        }
        __syncthreads();
        if (tid < NROI) {
            row_start[nb + tid] = e0 + start[tid];
            row_cnt[nb + tid] = cnt[tid];
            cur[tid] = start[tid];
        }
        __syncthreads();
        for (int i = tid; i < EPG; i += 256) {
            const int e = e0 + i, dl = dst[e] - nb;
            const int pos = atomicAdd(&cur[dl], 1);
            const int gi = e0 + pos;
            ssd[gi] = (src[e] - nb) | (dl << 16);
            const float4 q = make_float4(ea[e * 5], ea[e * 5 + 1], ea[e * 5 + 2], ea[e * 5 + 3]);
            *(float4*)&ea_s[(size_t)gi * 8] = q;
            ea_s[(size_t)gi * 8 + 4] = ea[e * 5 + 4];
        }
    } else {
        // ---- weight prep
        const int bb = blockIdx.x - (NN / 4 + NGRAPH);
        if (bb < 512) {
            const int n = bb;
            for (int k = tid; k < 64; k += 256) {
                const float v = (n < 256) ? Wl0[k * 256 + n] : Wr0[k * 256 + (n - 256)];
                Wt0[(size_t)n * 64 + k] = f2bf(v);
            }
        } else {
            const int n = bb - 512;
            for (int k = tid; k < 256; k += 256) {
                const float v = (n < 256) ? Wl1[k * 256 + n] : Wr1[k * 256 + (n - 256)];
                Wt1[(size_t)n * 256 + k] = f2bf(v);
            }
        }
    }
}

// ---------------------------------------------------------------- GINE (CSR, per-row wave) fused with MLP + LayerNorm -> bf16
__global__ __launch_bounds__(256) void k_gine_mlp_ln(
    const float* __restrict__ h0, const int* __restrict__ row_start,
    const int* __restrict__ row_cnt, const int* __restrict__ ssd,
    const float* __restrict__ ea_s,
    const float* __restrict__ We, const float* __restrict__ be,
    const float* __restrict__ W1, const float* __restrict__ b1,
    const float* __restrict__ W2, const float* __restrict__ b2,
    const float* __restrict__ lg_, const float* __restrict__ lb_,
    short* __restrict__ hn)
{
    const int tid = threadIdx.x, w = tid >> 6, lane = tid & 63;
    const int row = blockIdx.x * 4 + w;
    const int nb = (row / NROI) * NROI;
    const int st = row_start[row], cnt = row_cnt[row];
    const float w0 = We[lane], w1 = We[64 + lane], w2 = We[128 + lane],
                w3 = We[192 + lane], w4 = We[256 + lane];
    const float bec = be[lane];
    float g0 = 0.f, g1 = 0.f, g2 = 0.f, g3 = 0.f;
    int j = 0;
    for (; j + 4 <= cnt; j += 4) {
        const int i0 = st + j, i1 = st + j + 1, i2 = st + j + 2, i3 = st + j + 3;
        const int s0 = nb + (ssd[i0] & 0xffff), s1 = nb + (ssd[i1] & 0xffff),
                  s2 = nb + (ssd[i2] & 0xffff), s3 = nb + (ssd[i3] & 0xffff);
        const float h_0 = h0[s0 * 64 + lane], h_1 = h0[s1 * 64 + lane],
                    h_2 = h0[s2 * 64 + lane], h_3 = h0[s3 * 64 + lane];
        const float4 qa = *(const float4*)&ea_s[(size_t)i0 * 8];
        const float qa4 = ea_s[(size_t)i0 * 8 + 4];
        const float4 qb = *(const float4*)&ea_s[(size_t)i1 * 8];
        const float qb4 = ea_s[(size_t)i1 * 8 + 4];
        const float4 qc = *(const float4*)&ea_s[(size_t)i2 * 8];
        const float qc4 = ea_s[(size_t)i2 * 8 + 4];
        const float4 qd = *(const float4*)&ea_s[(size_t)i3 * 8];
        const float qd4 = ea_s[(size_t)i3 * 8 + 4];
        float e0_ = bec, e1_ = bec, e2_ = bec, e3_ = bec;
        e0_ = fmaf(qa.x, w0, e0_); e1_ = fmaf(qb.x, w0, e1_);
        e2_ = fmaf(qc.x, w0, e2_); e3_ = fmaf(qd.x, w0, e3_);
        e0_ = fmaf(qa.y, w1, e0_); e1_ = fmaf(qb.y, w1, e1_);
        e2_ = fmaf(qc.y, w1, e2_); e3_ = fmaf(qd.y, w1, e3_);
        e0_ = fmaf(qa.z, w2, e0_); e1_ = fmaf(qb.z, w2, e1_);
        e2_ = fmaf(qc.z, w2, e2_); e3_ = fmaf(qd.z, w2, e3_);
        e0_ = fmaf(qa.w, w3, e0_); e1_ = fmaf(qb.w, w3, e1_);
        e2_ = fmaf(qc.w, w3, e2_); e3_ = fmaf(qd.w, w3, e3_);
        e0_ = fmaf(qa4, w4, e0_);  e1_ = fmaf(qb4, w4, e1_);
        e2_ = fmaf(qc4, w4, e2_);  e3_ = fmaf(qd4, w4, e3_);
        g0 += fmaxf(h_0 + leaky(e0_, NEG), 0.f);
        g1 += fmaxf(h_1 + leaky(e1_, NEG), 0.f);
        g2 += fmaxf(h_2 + leaky(e2_, NEG), 0.f);
        g3 += fmaxf(h_3 + leaky(e3_, NEG), 0.f);
    }
    for (; j < cnt; j++) {
        const int idx = st + j;
        const int s = nb + (ssd[idx] & 0xffff);
        const float4 q = *(const float4*)&ea_s[(size_t)idx * 8];
        const float q4 = ea_s[(size_t)idx * 8 + 4];
        float em = bec;
        em = fmaf(q.x, w0, em); em = fmaf(q.y, w1, em); em = fmaf(q.z, w2, em);
        em = fmaf(q.w, w3, em); em = fmaf(q4, w4, em);
        g0 += fmaxf(h0[s * 64 + lane] + leaky(em, NEG), 0.f);
    }
    const float aggv = (g0 + g1) + (g2 + g3);
    __shared__ float v[4][64], t[4][64];
    v[w][lane] = h0[row * 64 + lane] + aggv;
    __syncthreads();
    float a = b1[lane];
    #pragma unroll 8
    for (int k = 0; k < 64; k++) a = fmaf(v[w][k], W1[k * 64 + lane], a);
    t[w][lane] = leaky(a, NEG);
    __syncthreads();
    float o = b2[lane];
    #pragma unroll 8
    for (int k = 0; k < 64; k++) o = fmaf(t[w][k], W2[k * 64 + lane], o);
    o = leaky(o, NEG);
    float s = o;
    #pragma unroll
    for (int off = 32; off; off >>= 1) s += __shfl_xor(s, off);
    const float mu = s * (1.f / 64.f);
    const float d = o - mu;
    float s2 = d * d;
    #pragma unroll
    for (int off = 32; off; off >>= 1) s2 += __shfl_xor(s2, off);
    hn[row * 64 + lane] = f2bf(d * rsqrtf(s2 * (1.f / 64.f) + 1e-5f) * lg_[lane] + lb_[lane]);
}

// ---------------------------------------------------------------- MFMA bf16 GEMM: [NN x D] @ [D x 512] -> X | Y (fp32)
template <int D, bool BN>
__global__ __launch_bounds__(256) void k_gemm(
    const short* __restrict__ A, const float* __restrict__ Vin,
    const float* __restrict__ stats, const float* __restrict__ bn_g,
    const float* __restrict__ bn_b,
    const short* __restrict__ Wt,
    float* __restrict__ X, float* __restrict__ Y)
{
    const int m0 = blockIdx.x * 16;
    const int w = threadIdx.x >> 6, lane = threadIdx.x & 63;
    const int n0 = w * 128;                     // waves 0,1 -> X; 2,3 -> Y
    const int r = lane & 15, q = lane >> 4;
    __shared__ float sc_s[256], sh_s[256];
    if constexpr (BN) {
        const int c = threadIdx.x;
        const float inv_n = 1.f / (float)NN;
        const float mu = stats[c] * inv_n;
        float var = stats[256 + c] * inv_n - mu * mu;
        var = fmaxf(var, 0.f);
        const float rsg = rsqrtf(var + 1e-5f) * bn_g[c];
        sc_s[c] = rsg;
        sh_s[c] = bn_b[c] - mu * rsg;
        __syncthreads();
    }
    floatx4 acc[8];
    #pragma unroll
    for (int t = 0; t < 8; t++) acc[t] = (floatx4){0.f, 0.f, 0.f, 0.f};
    const short* Arow = A + (size_t)(m0 + r) * D + q * 8;
    const float* Vrow = Vin + (size_t)(m0 + r) * D + q * 8;
    const short* Brow = Wt + (size_t)(n0 + r) * D + q * 8;
    #pragma unroll
    for (int k0 = 0; k0 < D; k0 += 32) {
        short8 a;
        if constexpr (BN) {
            const float4 v0 = *(const float4*)(Vrow + k0);
            const float4 v1 = *(const float4*)(Vrow + k0 + 4);
            const int cb = q * 8 + k0;
            a[0] = f2bf(leaky(fmaf(v0.x, sc_s[cb + 0], sh_s[cb + 0]), NEG));
            a[1] = f2bf(leaky(fmaf(v0.y, sc_s[cb + 1], sh_s[cb + 1]), NEG));
            a[2] = f2bf(leaky(fmaf(v0.z, sc_s[cb + 2], sh_s[cb + 2]), NEG));
            a[3] = f2bf(leaky(fmaf(v0.w, sc_s[cb + 3], sh_s[cb + 3]), NEG));
            a[4] = f2bf(leaky(fmaf(v1.x, sc_s[cb + 4], sh_s[cb + 4]), NEG));
            a[5] = f2bf(leaky(fmaf(v1.y, sc_s[cb + 5], sh_s[cb + 5]), NEG));
            a[6] = f2bf(leaky(fmaf(v1.z, sc_s[cb + 6], sh_s[cb + 6]), NEG));
            a[7] = f2bf(leaky(fmaf(v1.w, sc_s[cb + 7], sh_s[cb + 7]), NEG));
        } else {
            a = *(const short8*)(Arow + k0);
        }
        #pragma unroll
        for (int t = 0; t < 8; t++) {
            const short8 b = *(const short8*)(Brow + (size_t)t * 16 * D + k0);
            acc[t] = __builtin_amdgcn_mfma_f32_16x16x32_bf16(a, b, acc[t], 0, 0, 0);
        }
    }
    #pragma unroll
    for (int t = 0; t < 8; t++) {
        const int ncol = n0 + t * 16 + r;
        #pragma unroll
        for (int g2 = 0; g2 < 4; g2++) {
            const int row = m0 + q * 4 + g2;
            if (ncol < 256) X[(size_t)row * HC + ncol] = acc[t][g2];
            else            Y[(size_t)row * HC + (ncol - 256)] = acc[t][g2];
        }
    }
}

// ---------------------------------------------------------------- fused GATv2: block = (graph, head, half)
// phase A uses packed-f32 (VOP3P v_pk_*) arithmetic on channel pairs
__global__ __launch_bounds__(256, 4) void k_gat(
    const int* __restrict__ row_start, const int* __restrict__ row_cnt,
    const int* __restrict__ ssd, const float* __restrict__ ea_s,
    const float* __restrict__ We, const float* __restrict__ att,
    const float* __restrict__ bias,
    const float* __restrict__ X, const float* __restrict__ Y,
    float* __restrict__ V, float* __restrict__ stats)
{
    const int g = blockIdx.x >> 3;
    const int h = (blockIdx.x >> 1) & 3;
    const int half = blockIdx.x & 1;
    const int tid = threadIdx.x, w = tid >> 6, lane = tid & 63;
    const int nb = g * NROI, e0 = g * EPG, hc = h * 64;
    const int r0 = half * 58, r1 = r0 + 58;
    const int es = row_start[nb + r0];
    const int ee = (r1 < NROI) ? row_start[nb + r1] : e0 + EPG;

    __shared__ float Xs[NROI * XPAD];
    __shared__ float lg[EPB];
    __shared__ float inv_s[58];

    for (int r = w; r < NROI; r += 4)
        Xs[r * XPAD + lane] = X[(size_t)(nb + r) * HC + hc + lane];
    __syncthreads();

    // ---- phase A: logits, lane = edge, packed-f32 channel pairs
    const int ne = ee - es;
    for (int i = tid; i < ne; i += 256) {
        const int e = es + i;
        const int sd = ssd[e];
        const int sl = sd & 0xffff, dl = sd >> 16;
        const float4 q = *(const float4*)&ea_s[(size_t)e * 8];
        const float q4 = ea_s[(size_t)e * 8 + 4];
        const floatx2 qx = {q.x, q.x}, qy = {q.y, q.y}, qz = {q.z, q.z},
                      qw = {q.w, q.w}, qv = {q4, q4};
        const float* yrow = &Y[(size_t)(nb + dl) * HC + hc];
        const int xb = sl * XPAD;
        floatx2 lacc = {0.f, 0.f};
        #pragma unroll 8
        for (int c = 0; c < 64; c += 2) {
            const floatx2 y2 = *(const floatx2*)(yrow + c);             // 8B-aligned
            const floatx2 xs2 = {Xs[xb + c], Xs[xb + c + 1]};           // ds_read2_b32
            const floatx2 w0 = *(const floatx2*)(We + 0 * HC + hc + c);
            const floatx2 w1 = *(const floatx2*)(We + 1 * HC + hc + c);
            const floatx2 w2 = *(const floatx2*)(We + 2 * HC + hc + c);
            const floatx2 w3 = *(const floatx2*)(We + 3 * HC + hc + c);
            const floatx2 w4 = *(const floatx2*)(We + 4 * HC + hc + c);
            floatx2 ep = qx * w0;
            ep += qy * w1;
            ep += qz * w2;
            ep += qw * w3;
            ep += qv * w4;
            const floatx2 z = xs2 + y2 + ep;
            const floatx2 zs = z * (floatx2){NEGA, NEGA};
            const floatx2 lk = {fmaxf(z.x, zs.x), fmaxf(z.y, zs.y)};
            const floatx2 a2 = *(const floatx2*)(att + hc + c);
            lacc += a2 * lk;
        }
        lg[i] = lacc.x + lacc.y;
    }
    __syncthreads();

    // ---- phase B: per-row max / exp / sum; store reciprocal
    for (int r = r0 + w; r < r1; r += 4) {
        const int stl = row_start[nb + r] - es;
        const int cnt = row_cnt[nb + r];
        float m = -INFINITY;
        for (int j = lane; j < cnt; j += 64) m = fmaxf(m, lg[stl + j]);
        #pragma unroll
        for (int off = 32; off; off >>= 1) m = fmaxf(m, __shfl_xor(m, off));
        float s = 0.f;
        for (int j = lane; j < cnt; j += 64) {
            const float e_ = __expf(lg[stl + j] - m);
            lg[stl + j] = e_;
            s += e_;
        }
        #pragma unroll
        for (int off = 32; off; off >>= 1) s += __shfl_xor(s, off);
        if (lane == 0) inv_s[r - r0] = 1.f / (s + 1e-16f);
    }
    __syncthreads();

    // ---- phase C: numerator (wave per row, lane = channel) + BN partials
    float ps = 0.f, ps2 = 0.f;
    const float bb = bias[hc + lane];
    for (int r = r0 + w; r < r1; r += 4) {
        const int st = row_start[nb + r];
        const int cnt = row_cnt[nb + r];
        const int stl = st - es;
        float a0 = 0.f, a1 = 0.f, a2 = 0.f, a3 = 0.f;
        int j = 0;
        for (; j + 4 <= cnt; j += 4) {
            const int s0 = ssd[st + j] & 0xffff, s1 = ssd[st + j + 1] & 0xffff,
                      s2 = ssd[st + j + 2] & 0xffff, s3 = ssd[st + j + 3] & 0xffff;
            a0 = fmaf(Xs[s0 * XPAD + lane], lg[stl + j], a0);
            a1 = fmaf(Xs[s1 * XPAD + lane], lg[stl + j + 1], a1);
            a2 = fmaf(Xs[s2 * XPAD + lane], lg[stl + j + 2], a2);
            a3 = fmaf(Xs[s3 * XPAD + lane], lg[stl + j + 3], a3);
        }
        for (; j < cnt; j++)
            a0 = fmaf(Xs[(ssd[st + j] & 0xffff) * XPAD + lane], lg[stl + j], a0);
        const float vv = ((a0 + a1) + (a2 + a3)) * inv_s[r - r0] + bb;
        V[(size_t)(nb + r) * HC + hc + lane] = vv;
        ps += vv;
        ps2 += vv * vv;
    }
    __syncthreads();                 // lg free; reuse as reduction buffer
    lg[tid] = ps;
    lg[256 + tid] = ps2;
    __syncthreads();
    if (tid < 64) {
        float s1 = 0.f, s2 = 0.f;
        #pragma unroll
        for (int w2 = 0; w2 < 4; w2++) {
            s1 += lg[w2 * 64 + tid];
            s2 += lg[256 + w2 * 64 + tid];
        }
        atomicAdd(&stats[hc + tid], s1);
        atomicAdd(&stats[256 + hc + tid], s2);
    }
}

// ---------------------------------------------------------------- BN + leaky + mean-pool + classifier
__global__ __launch_bounds__(256) void k_pool_fc(
    const float* __restrict__ V, const float* __restrict__ stats,
    const float* __restrict__ bg, const float* __restrict__ bb,
    const float* __restrict__ fW, const float* __restrict__ fb,
    float* __restrict__ out)
{
    const int g = blockIdx.x, c = threadIdx.x;
    const float inv_n = 1.f / (float)NN;
    const float mu = stats[c] * inv_n;
    float var = stats[256 + c] * inv_n - mu * mu;
    var = fmaxf(var, 0.f);
    const float rsg = rsqrtf(var + 1e-5f) * bg[c];
    const float bbc = bb[c];
    float s = 0.f;
    for (int r = 0; r < NROI; r++) {
        const float vv = (V[(size_t)(g * NROI + r) * HC + c] - mu) * rsg + bbc;
        s += leaky(vv, NEG);
    }
    s *= (1.f / (float)NROI);
    __shared__ float red[256];
    for (int o = 0; o < 2; o++) {
        red[c] = s * fW[c * 2 + o];
        __syncthreads();
        for (int off = 128; off; off >>= 1) {
            if (c < off) red[c] += red[c + off];
            __syncthreads();
        }
        if (c == 0) out[g * 2 + o] = red[0] + fb[o];
        __syncthreads();
    }
}

extern "C" void kernel_launch(void* const* d_in, const int* in_sizes, int n_in,
                              void* d_out, int out_size, void* d_ws, size_t ws_size,
                              hipStream_t stream) {
    const float* x         = (const float*)d_in[0];
    const int*   edge_idx  = (const int*)d_in[1];
    const float* edge_attr = (const float*)d_in[2];
    const int*   node_grp  = (const int*)d_in[4];
    const float* group_emb = (const float*)d_in[5];
    const float* W_embed   = (const float*)d_in[6];
    const float* b_embed   = (const float*)d_in[7];
    const float* We_enc    = (const float*)d_in[8];
    const float* be_enc    = (const float*)d_in[9];
    const float* W1        = (const float*)d_in[10];
    const float* b1        = (const float*)d_in[11];
    const float* W2        = (const float*)d_in[12];
    const float* b2        = (const float*)d_in[13];
    const float* ln_g      = (const float*)d_in[14];
    const float* ln_b      = (const float*)d_in[15];
    const float* l0_Wl     = (const float*)d_in[16];
    const float* l0_Wr     = (const float*)d_in[17];
    const float* l0_We     = (const float*)d_in[18];
    const float* l0_att    = (const float*)d_in[19];
    const float* l0_b      = (const float*)d_in[20];
    const float* l0_bn_g   = (const float*)d_in[21];
    const float* l0_bn_b   = (const float*)d_in[22];
    const float* l1_Wl     = (const float*)d_in[23];
    const float* l1_Wr     = (const float*)d_in[24];
    const float* l1_We     = (const float*)d_in[25];
    const float* l1_att    = (const float*)d_in[26];
    const float* l1_b      = (const float*)d_in[27];
    const float* l1_bn_g   = (const float*)d_in[28];
    const float* l1_bn_b   = (const float*)d_in[29];
    const float* fc2_W     = (const float*)d_in[30];
    const float* fc2_b     = (const float*)d_in[31];

    const int* src = edge_idx;
    const int* dst = edge_idx + NE;

    float* ws     = (float*)d_ws;
    float* h0     = ws;                       // 64*NN f32
    float* X      = h0 + (size_t)64 * NN;     // 256*NN f32
    float* Y      = X + (size_t)HC * NN;      // 256*NN f32
    float* V      = Y + (size_t)HC * NN;      // 256*NN f32
    float* stats0 = V + (size_t)HC * NN;      // 512
    float* stats1 = stats0 + 512;             // 512
    float* ea_s   = stats1 + 512;             // 8*NE f32
    int* row_start = (int*)(ea_s + (size_t)8 * NE);  // NN
    int* row_cnt   = row_start + NN;                 // NN
    int* ssd       = row_cnt + NN;                   // NE
    short* hn_b    = (short*)(ssd + NE);             // 64*NN bf16
    short* Wt0     = hn_b + (size_t)64 * NN;         // 512*64 bf16
    short* Wt1     = Wt0 + 512 * 64;                 // 512*256 bf16

    float* out = (float*)d_out;

    k_front<<<NN / 4 + NGRAPH + 1024, 256, 0, stream>>>(
        x, node_grp, group_emb, W_embed, b_embed, h0,
        src, dst, edge_attr, row_start, row_cnt, ssd, ea_s, stats0,
        l0_Wl, l0_Wr, l1_Wl, l1_Wr, Wt0, Wt1);
    k_gine_mlp_ln<<<NN / 4, 256, 0, stream>>>(h0, row_start, row_cnt, ssd, ea_s,
                                              We_enc, be_enc, W1, b1, W2, b2, ln_g, ln_b, hn_b);

    // GAT layer 0
    k_gemm<64, false><<<NN / 16, 256, 0, stream>>>(hn_b, nullptr, nullptr, nullptr, nullptr,
                                                   Wt0, X, Y);
    k_gat<<<NGRAPH * 8, 256, 0, stream>>>(row_start, row_cnt, ssd, ea_s,
                                          l0_We, l0_att, l0_b, X, Y, V, stats0);

    // GAT layer 1 (BN+leaky+bf16 of layer-0 output fused into GEMM A-load)
    k_gemm<256, true><<<NN / 16, 256, 0, stream>>>(nullptr, V, stats0, l0_bn_g, l0_bn_b,
                                                   Wt1, X, Y);
    k_gat<<<NGRAPH * 8, 256, 0, stream>>>(row_start, row_cnt, ssd, ea_s,
                                          l1_We, l1_att, l1_b, X, Y, V, stats1);

    // BN+leaky of layer-1 output fused into pooling
    k_pool_fc<<<NGRAPH, 256, 0, stream>>>(V, stats1, l1_bn_g, l1_bn_b, fc2_W, fc2_b, out);
}

// Round 10
// 430.066 us; speedup vs baseline: 1.2523x; 1.0015x over previous
//
#include <hip/hip_runtime.h>
#include <hip/hip_bf16.h>

#define NN     14848      // nodes
#define NE     475136     // edges
#define NROI   116        // nodes per graph
#define NGRAPH 128        // graphs
#define EPG    3712       // edges per graph (116*32)
#define HID    64
#define HC     256
#define NEG    0.01f
#define NEGA   0.2f
#define EPB    2304       // max edges per half-graph block (mean 1856)
#define XPAD   65         // Xs row stride (R5/R7-measured best)

typedef __attribute__((ext_vector_type(8))) short short8;
typedef __attribute__((ext_vector_type(4))) float floatx4;
typedef __attribute__((ext_vector_type(2))) float floatx2;

// leaky(x) = max(x, s*x) for 0<s<1 — 2 VALU, no branch
__device__ __forceinline__ float leaky(float x, float s) { return fmaxf(x, s * x); }

// round-to-nearest-even float -> bf16 bits
__device__ __forceinline__ short f2bf(float f) {
    unsigned u = __float_as_uint(f);
    unsigned r = (u + 0x7fffu + ((u >> 16) & 1u)) >> 16;
    return (short)r;
}

// ---------------------------------------------------------------- front: embed + CSR + weight prep (independent; one dispatch)
__global__ __launch_bounds__(256) void k_front(
    const float* __restrict__ x, const int* __restrict__ ng,
    const float* __restrict__ gemb, const float* __restrict__ W,
    const float* __restrict__ b, float* __restrict__ h0,
    const int* __restrict__ src, const int* __restrict__ dst,
    const float* __restrict__ ea,
    int* __restrict__ row_start, int* __restrict__ row_cnt,
    int* __restrict__ ssd, float* __restrict__ ea_s,
    float* __restrict__ stats01,
    const float* __restrict__ Wl0, const float* __restrict__ Wr0,
    const float* __restrict__ Wl1, const float* __restrict__ Wr1,
    short* __restrict__ Wt0, short* __restrict__ Wt1)
{
    const int tid = threadIdx.x;
    if (blockIdx.x < NN / 4) {
        // ---- embed
        const int w = tid >> 6, c = tid & 63;
        const int n = blockIdx.x * 4 + w;
        __shared__ float in[4][132];
        for (int k = c; k < NROI; k += 64) in[w][k] = x[n * NROI + k];
        if (c < 16) in[w][NROI + c] = gemb[ng[n] * 16 + c];
        __syncthreads();
        float acc = b[c];
        #pragma unroll 4
        for (int k = 0; k < 132; k++) acc = fmaf(in[w][k], W[k * 64 + c], acc);
        h0[n * 64 + c] = leaky(acc, NEG);
    } else if (blockIdx.x < NN / 4 + NGRAPH) {
        // ---- CSR
        const int g = blockIdx.x - NN / 4;
        if (g < 2) {
            for (int i = tid; i < 512; i += 256) stats01[g * 512 + i] = 0.f;
        }
        const int e0 = g * EPG, nb = g * NROI;
        __shared__ int cnt[NROI], start[NROI], cur[NROI];
        if (tid < NROI) cnt[tid] = 0;
        __syncthreads();
        for (int i = tid; i < EPG; i += 256) atomicAdd(&cnt[dst[e0 + i] - nb], 1);
        __syncthreads();
        if (tid == 0) {
            int s = 0;
            for (int r = 0; r < NROI; r++) { start[r] = s; s += cnt[r]; }
        }
        __syncthreads();
        if (tid < NROI) {
            row_start[nb + tid] = e0 + start[tid];
            row_cnt[nb + tid] = cnt[tid];
            cur[tid] = start[tid];
        }
        __syncthreads();
        for (int i = tid; i < EPG; i += 256) {
            const int e = e0 + i, dl = dst[e] - nb;
            const int pos = atomicAdd(&cur[dl], 1);
            const int gi = e0 + pos;
            ssd[gi] = (src[e] - nb) | (dl << 16);
            const float4 q = make_float4(ea[e * 5], ea[e * 5 + 1], ea[e * 5 + 2], ea[e * 5 + 3]);
            *(float4*)&ea_s[(size_t)gi * 8] = q;
            ea_s[(size_t)gi * 8 + 4] = ea[e * 5 + 4];
        }
    } else {
        // ---- weight prep
        const int bb = blockIdx.x - (NN / 4 + NGRAPH);
        if (bb < 512) {
            const int n = bb;
            for (int k = tid; k < 64; k += 256) {
                const float v = (n < 256) ? Wl0[k * 256 + n] : Wr0[k * 256 + (n - 256)];
                Wt0[(size_t)n * 64 + k] = f2bf(v);
            }
        } else {
            const int n = bb - 512;
            for (int k = tid; k < 256; k += 256) {
                const float v = (n < 256) ? Wl1[k * 256 + n] : Wr1[k * 256 + (n - 256)];
                Wt1[(size_t)n * 256 + k] = f2bf(v);
            }
        }
    }
}

// ---------------------------------------------------------------- GINE (CSR, per-row wave) fused with MLP + LayerNorm -> bf16
__global__ __launch_bounds__(256) void k_gine_mlp_ln(
    const float* __restrict__ h0, const int* __restrict__ row_start,
    const int* __restrict__ row_cnt, const int* __restrict__ ssd,
    const float* __restrict__ ea_s,
    const float* __restrict__ We, const float* __restrict__ be,
    const float* __restrict__ W1, const float* __restrict__ b1,
    const float* __restrict__ W2, const float* __restrict__ b2,
    const float* __restrict__ lg_, const float* __restrict__ lb_,
    short* __restrict__ hn)
{
    const int tid = threadIdx.x, w = tid >> 6, lane = tid & 63;
    const int row = blockIdx.x * 4 + w;
    const int nb = (row / NROI) * NROI;
    const int st = row_start[row], cnt = row_cnt[row];
    const float w0 = We[lane], w1 = We[64 + lane], w2 = We[128 + lane],
                w3 = We[192 + lane], w4 = We[256 + lane];
    const float bec = be[lane];
    float g0 = 0.f, g1 = 0.f, g2 = 0.f, g3 = 0.f;
    int j = 0;
    for (; j + 4 <= cnt; j += 4) {
        const int i0 = st + j, i1 = st + j + 1, i2 = st + j + 2, i3 = st + j + 3;
        const int s0 = nb + (ssd[i0] & 0xffff), s1 = nb + (ssd[i1] & 0xffff),
                  s2 = nb + (ssd[i2] & 0xffff), s3 = nb + (ssd[i3] & 0xffff);
        const float h_0 = h0[s0 * 64 + lane], h_1 = h0[s1 * 64 + lane],
                    h_2 = h0[s2 * 64 + lane], h_3 = h0[s3 * 64 + lane];
        const float4 qa = *(const float4*)&ea_s[(size_t)i0 * 8];
        const float qa4 = ea_s[(size_t)i0 * 8 + 4];
        const float4 qb = *(const float4*)&ea_s[(size_t)i1 * 8];
        const float qb4 = ea_s[(size_t)i1 * 8 + 4];
        const float4 qc = *(const float4*)&ea_s[(size_t)i2 * 8];
        const float qc4 = ea_s[(size_t)i2 * 8 + 4];
        const float4 qd = *(const float4*)&ea_s[(size_t)i3 * 8];
        const float qd4 = ea_s[(size_t)i3 * 8 + 4];
        float e0_ = bec, e1_ = bec, e2_ = bec, e3_ = bec;
        e0_ = fmaf(qa.x, w0, e0_); e1_ = fmaf(qb.x, w0, e1_);
        e2_ = fmaf(qc.x, w0, e2_); e3_ = fmaf(qd.x, w0, e3_);
        e0_ = fmaf(qa.y, w1, e0_); e1_ = fmaf(qb.y, w1, e1_);
        e2_ = fmaf(qc.y, w1, e2_); e3_ = fmaf(qd.y, w1, e3_);
        e0_ = fmaf(qa.z, w2, e0_); e1_ = fmaf(qb.z, w2, e1_);
        e2_ = fmaf(qc.z, w2, e2_); e3_ = fmaf(qd.z, w2, e3_);
        e0_ = fmaf(qa.w, w3, e0_); e1_ = fmaf(qb.w, w3, e1_);
        e2_ = fmaf(qc.w, w3, e2_); e3_ = fmaf(qd.w, w3, e3_);
        e0_ = fmaf(qa4, w4, e0_);  e1_ = fmaf(qb4, w4, e1_);
        e2_ = fmaf(qc4, w4, e2_);  e3_ = fmaf(qd4, w4, e3_);
        g0 += fmaxf(h_0 + leaky(e0_, NEG), 0.f);
        g1 += fmaxf(h_1 + leaky(e1_, NEG), 0.f);
        g2 += fmaxf(h_2 + leaky(e2_, NEG), 0.f);
        g3 += fmaxf(h_3 + leaky(e3_, NEG), 0.f);
    }
    for (; j < cnt; j++) {
        const int idx = st + j;
        const int s = nb + (ssd[idx] & 0xffff);
        const float4 q = *(const float4*)&ea_s[(size_t)idx * 8];
        const float q4 = ea_s[(size_t)idx * 8 + 4];
        float em = bec;
        em = fmaf(q.x, w0, em); em = fmaf(q.y, w1, em); em = fmaf(q.z, w2, em);
        em = fmaf(q.w, w3, em); em = fmaf(q4, w4, em);
        g0 += fmaxf(h0[s * 64 + lane] + leaky(em, NEG), 0.f);
    }
    const float aggv = (g0 + g1) + (g2 + g3);
    __shared__ float v[4][64], t[4][64];
    v[w][lane] = h0[row * 64 + lane] + aggv;
    __syncthreads();
    float a = b1[lane];
    #pragma unroll 8
    for (int k = 0; k < 64; k++) a = fmaf(v[w][k], W1[k * 64 + lane], a);
    t[w][lane] = leaky(a, NEG);
    __syncthreads();
    float o = b2[lane];
    #pragma unroll 8
    for (int k = 0; k < 64; k++) o = fmaf(t[w][k], W2[k * 64 + lane], o);
    o = leaky(o, NEG);
    float s = o;
    #pragma unroll
    for (int off = 32; off; off >>= 1) s += __shfl_xor(s, off);
    const float mu = s * (1.f / 64.f);
    const float d = o - mu;
    float s2 = d * d;
    #pragma unroll
    for (int off = 32; off; off >>= 1) s2 += __shfl_xor(s2, off);
    hn[row * 64 + lane] = f2bf(d * rsqrtf(s2 * (1.f / 64.f) + 1e-5f) * lg_[lane] + lb_[lane]);
}

// ---------------------------------------------------------------- MFMA bf16 GEMM: [NN x D] @ [D x 512] -> X | Y (fp32)
template <int D, bool BN>
__global__ __launch_bounds__(256) void k_gemm(
    const short* __restrict__ A, const float* __restrict__ Vin,
    const float* __restrict__ stats, const float* __restrict__ bn_g,
    const float* __restrict__ bn_b,
    const short* __restrict__ Wt,
    float* __restrict__ X, float* __restrict__ Y)
{
    const int m0 = blockIdx.x * 16;
    const int w = threadIdx.x >> 6, lane = threadIdx.x & 63;
    const int n0 = w * 128;                     // waves 0,1 -> X; 2,3 -> Y
    const int r = lane & 15, q = lane >> 4;
    __shared__ float sc_s[256], sh_s[256];
    if constexpr (BN) {
        const int c = threadIdx.x;
        const float inv_n = 1.f / (float)NN;
        const float mu = stats[c] * inv_n;
        float var = stats[256 + c] * inv_n - mu * mu;
        var = fmaxf(var, 0.f);
        const float rsg = rsqrtf(var + 1e-5f) * bn_g[c];
        sc_s[c] = rsg;
        sh_s[c] = bn_b[c] - mu * rsg;
        __syncthreads();
    }
    floatx4 acc[8];
    #pragma unroll
    for (int t = 0; t < 8; t++) acc[t] = (floatx4){0.f, 0.f, 0.f, 0.f};
    const short* Arow = A + (size_t)(m0 + r) * D + q * 8;
    const float* Vrow = Vin + (size_t)(m0 + r) * D + q * 8;
    const short* Brow = Wt + (size_t)(n0 + r) * D + q * 8;
    #pragma unroll
    for (int k0 = 0; k0 < D; k0 += 32) {
        short8 a;
        if constexpr (BN) {
            const float4 v0 = *(const float4*)(Vrow + k0);
            const float4 v1 = *(const float4*)(Vrow + k0 + 4);
            const int cb = q * 8 + k0;
            a[0] = f2bf(leaky(fmaf(v0.x, sc_s[cb + 0], sh_s[cb + 0]), NEG));
            a[1] = f2bf(leaky(fmaf(v0.y, sc_s[cb + 1], sh_s[cb + 1]), NEG));
            a[2] = f2bf(leaky(fmaf(v0.z, sc_s[cb + 2], sh_s[cb + 2]), NEG));
            a[3] = f2bf(leaky(fmaf(v0.w, sc_s[cb + 3], sh_s[cb + 3]), NEG));
            a[4] = f2bf(leaky(fmaf(v1.x, sc_s[cb + 4], sh_s[cb + 4]), NEG));
            a[5] = f2bf(leaky(fmaf(v1.y, sc_s[cb + 5], sh_s[cb + 5]), NEG));
            a[6] = f2bf(leaky(fmaf(v1.z, sc_s[cb + 6], sh_s[cb + 6]), NEG));
            a[7] = f2bf(leaky(fmaf(v1.w, sc_s[cb + 7], sh_s[cb + 7]), NEG));
        } else {
            a = *(const short8*)(Arow + k0);
        }
        #pragma unroll
        for (int t = 0; t < 8; t++) {
            const short8 b = *(const short8*)(Brow + (size_t)t * 16 * D + k0);
            acc[t] = __builtin_amdgcn_mfma_f32_16x16x32_bf16(a, b, acc[t], 0, 0, 0);
        }
    }
    #pragma unroll
    for (int t = 0; t < 8; t++) {
        const int ncol = n0 + t * 16 + r;
        #pragma unroll
        for (int g2 = 0; g2 < 4; g2++) {
            const int row = m0 + q * 4 + g2;
            if (ncol < 256) X[(size_t)row * HC + ncol] = acc[t][g2];
            else            Y[(size_t)row * HC + (ncol - 256)] = acc[t][g2];
        }
    }
}

// ---------------------------------------------------------------- fused GATv2: XCD-swizzled blocks, 2-edge-interleaved phase A
// blockIdx = sub*128 + g  (g = graph, sub = head*2+half) -> all 8 blocks of a
// graph share blockIdx%8 -> same XCD L2 (ea_s/ssd/X fetched once per graph)
__global__ __launch_bounds__(256, 4) void k_gat(
    const int* __restrict__ row_start, const int* __restrict__ row_cnt,
    const int* __restrict__ ssd, const float* __restrict__ ea_s,
    const float* __restrict__ We, const float* __restrict__ att,
    const float* __restrict__ bias,
    const float* __restrict__ X, const float* __restrict__ Y,
    float* __restrict__ V, float* __restrict__ stats)
{
    const int g = blockIdx.x & 127;
    const int sub = blockIdx.x >> 7;
    const int h = sub >> 1;
    const int half = sub & 1;
    const int tid = threadIdx.x, w = tid >> 6, lane = tid & 63;
    const int nb = g * NROI, e0 = g * EPG, hc = h * 64;
    const int r0 = half * 58, r1 = r0 + 58;
    const int es = row_start[nb + r0];
    const int ee = (r1 < NROI) ? row_start[nb + r1] : e0 + EPG;

    __shared__ float Xs[NROI * XPAD];
    __shared__ float lg[EPB];
    __shared__ float inv_s[58];

    for (int r = w; r < NROI; r += 4)
        Xs[r * XPAD + lane] = X[(size_t)(nb + r) * HC + hc + lane];
    __syncthreads();

    // ---- phase A: logits, lane = edge, packed-f32, 2 edges per thread in flight
    const int ne = ee - es;
    for (int i = tid; i < ne; i += 512) {
        const int i2 = i + 256;
        const bool two = i2 < ne;
        const int e1 = es + i;
        const int e2 = es + (two ? i2 : i);
        const int sd1 = ssd[e1], sd2 = ssd[e2];
        const int xb1 = (sd1 & 0xffff) * XPAD, xb2 = (sd2 & 0xffff) * XPAD;
        const float4 qa = *(const float4*)&ea_s[(size_t)e1 * 8];
        const float qa4 = ea_s[(size_t)e1 * 8 + 4];
        const float4 qb = *(const float4*)&ea_s[(size_t)e2 * 8];
        const float qb4 = ea_s[(size_t)e2 * 8 + 4];
        const float* yr1 = &Y[(size_t)(nb + (sd1 >> 16)) * HC + hc];
        const float* yr2 = &Y[(size_t)(nb + (sd2 >> 16)) * HC + hc];
        const floatx2 qax = {qa.x, qa.x}, qay = {qa.y, qa.y}, qaz = {qa.z, qa.z},
                      qaw = {qa.w, qa.w}, qav = {qa4, qa4};
        const floatx2 qbx = {qb.x, qb.x}, qby = {qb.y, qb.y}, qbz = {qb.z, qb.z},
                      qbw = {qb.w, qb.w}, qbv = {qb4, qb4};
        floatx2 acc1 = {0.f, 0.f}, acc2 = {0.f, 0.f};
        #pragma unroll 8
        for (int c = 0; c < 64; c += 2) {
            const floatx2 w0 = *(const floatx2*)(We + 0 * HC + hc + c);
            const floatx2 w1 = *(const floatx2*)(We + 1 * HC + hc + c);
            const floatx2 w2 = *(const floatx2*)(We + 2 * HC + hc + c);
            const floatx2 w3 = *(const floatx2*)(We + 3 * HC + hc + c);
            const floatx2 w4 = *(const floatx2*)(We + 4 * HC + hc + c);
            const floatx2 a2 = *(const floatx2*)(att + hc + c);
            // edge 1
            const floatx2 y1 = *(const floatx2*)(yr1 + c);
            const floatx2 x1 = {Xs[xb1 + c], Xs[xb1 + c + 1]};
            floatx2 ep1 = qax * w0;
            ep1 += qay * w1; ep1 += qaz * w2; ep1 += qaw * w3; ep1 += qav * w4;
            const floatx2 z1 = x1 + y1 + ep1;
            const floatx2 zs1 = z1 * (floatx2){NEGA, NEGA};
            const floatx2 lk1 = {fmaxf(z1.x, zs1.x), fmaxf(z1.y, zs1.y)};
            acc1 += a2 * lk1;
            // edge 2
            const floatx2 y2 = *(const floatx2*)(yr2 + c);
            const floatx2 x2 = {Xs[xb2 + c], Xs[xb2 + c + 1]};
            floatx2 ep2 = qbx * w0;
            ep2 += qby * w1; ep2 += qbz * w2; ep2 += qbw * w3; ep2 += qbv * w4;
            const floatx2 z2 = x2 + y2 + ep2;
            const floatx2 zs2 = z2 * (floatx2){NEGA, NEGA};
            const floatx2 lk2 = {fmaxf(z2.x, zs2.x), fmaxf(z2.y, zs2.y)};
            acc2 += a2 * lk2;
        }
        lg[i] = acc1.x + acc1.y;
        if (two) lg[i2] = acc2.x + acc2.y;
    }
    __syncthreads();

    // ---- phase B: per-row max / exp / sum; store reciprocal
    for (int r = r0 + w; r < r1; r += 4) {
        const int stl = row_start[nb + r] - es;
        const int cnt = row_cnt[nb + r];
        float m = -INFINITY;
        for (int j = lane; j < cnt; j += 64) m = fmaxf(m, lg[stl + j]);
        #pragma unroll
        for (int off = 32; off; off >>= 1) m = fmaxf(m, __shfl_xor(m, off));
        float s = 0.f;
        for (int j = lane; j < cnt; j += 64) {
            const float e_ = __expf(lg[stl + j] - m);
            lg[stl + j] = e_;
            s += e_;
        }
        #pragma unroll
        for (int off = 32; off; off >>= 1) s += __shfl_xor(s, off);
        if (lane == 0) inv_s[r - r0] = 1.f / (s + 1e-16f);
    }
    __syncthreads();

    // ---- phase C: numerator (wave per row, lane = channel) + BN partials
    float ps = 0.f, ps2 = 0.f;
    const float bb = bias[hc + lane];
    for (int r = r0 + w; r < r1; r += 4) {
        const int st = row_start[nb + r];
        const int cnt = row_cnt[nb + r];
        const int stl = st - es;
        float a0 = 0.f, a1 = 0.f, a2 = 0.f, a3 = 0.f;
        int j = 0;
        for (; j + 4 <= cnt; j += 4) {
            const int s0 = ssd[st + j] & 0xffff, s1 = ssd[st + j + 1] & 0xffff,
                      s2 = ssd[st + j + 2] & 0xffff, s3 = ssd[st + j + 3] & 0xffff;
            a0 = fmaf(Xs[s0 * XPAD + lane], lg[stl + j], a0);
            a1 = fmaf(Xs[s1 * XPAD + lane], lg[stl + j + 1], a1);
            a2 = fmaf(Xs[s2 * XPAD + lane], lg[stl + j + 2], a2);
            a3 = fmaf(Xs[s3 * XPAD + lane], lg[stl + j + 3], a3);
        }
        for (; j < cnt; j++)
            a0 = fmaf(Xs[(ssd[st + j] & 0xffff) * XPAD + lane], lg[stl + j], a0);
        const float vv = ((a0 + a1) + (a2 + a3)) * inv_s[r - r0] + bb;
        V[(size_t)(nb + r) * HC + hc + lane] = vv;
        ps += vv;
        ps2 += vv * vv;
    }
    __syncthreads();                 // lg free; reuse as reduction buffer
    lg[tid] = ps;
    lg[256 + tid] = ps2;
    __syncthreads();
    if (tid < 64) {
        float s1 = 0.f, s2 = 0.f;
        #pragma unroll
        for (int w2 = 0; w2 < 4; w2++) {
            s1 += lg[w2 * 64 + tid];
            s2 += lg[256 + w2 * 64 + tid];
        }
        atomicAdd(&stats[hc + tid], s1);
        atomicAdd(&stats[256 + hc + tid], s2);
    }
}

// ---------------------------------------------------------------- BN + leaky + mean-pool + classifier
__global__ __launch_bounds__(256) void k_pool_fc(
    const float* __restrict__ V, const float* __restrict__ stats,
    const float* __restrict__ bg, const float* __restrict__ bb,
    const float* __restrict__ fW, const float* __restrict__ fb,
    float* __restrict__ out)
{
    const int g = blockIdx.x, c = threadIdx.x;
    const float inv_n = 1.f / (float)NN;
    const float mu = stats[c] * inv_n;
    float var = stats[256 + c] * inv_n - mu * mu;
    var = fmaxf(var, 0.f);
    const float rsg = rsqrtf(var + 1e-5f) * bg[c];
    const float bbc = bb[c];
    float s = 0.f;
    for (int r = 0; r < NROI; r++) {
        const float vv = (V[(size_t)(g * NROI + r) * HC + c] - mu) * rsg + bbc;
        s += leaky(vv, NEG);
    }
    s *= (1.f / (float)NROI);
    __shared__ float red[256];
    for (int o = 0; o < 2; o++) {
        red[c] = s * fW[c * 2 + o];
        __syncthreads();
        for (int off = 128; off; off >>= 1) {
            if (c < off) red[c] += red[c + off];
            __syncthreads();
        }
        if (c == 0) out[g * 2 + o] = red[0] + fb[o];
        __syncthreads();
    }
}

extern "C" void kernel_launch(void* const* d_in, const int* in_sizes, int n_in,
                              void* d_out, int out_size, void* d_ws, size_t ws_size,
                              hipStream_t stream) {
    const float* x         = (const float*)d_in[0];
    const int*   edge_idx  = (const int*)d_in[1];
    const float* edge_attr = (const float*)d_in[2];
    const int*   node_grp  = (const int*)d_in[4];
    const float* group_emb = (const float*)d_in[5];
    const float* W_embed   = (const float*)d_in[6];
    const float* b_embed   = (const float*)d_in[7];
    const float* We_enc    = (const float*)d_in[8];
    const float* be_enc    = (const float*)d_in[9];
    const float* W1        = (const float*)d_in[10];
    const float* b1        = (const float*)d_in[11];
    const float* W2        = (const float*)d_in[12];
    const float* b2        = (const float*)d_in[13];
    const float* ln_g      = (const float*)d_in[14];
    const float* ln_b      = (const float*)d_in[15];
    const float* l0_Wl     = (const float*)d_in[16];
    const float* l0_Wr     = (const float*)d_in[17];
    const float* l0_We     = (const float*)d_in[18];
    const float* l0_att    = (const float*)d_in[19];
    const float* l0_b      = (const float*)d_in[20];
    const float* l0_bn_g   = (const float*)d_in[21];
    const float* l0_bn_b   = (const float*)d_in[22];
    const float* l1_Wl     = (const float*)d_in[23];
    const float* l1_Wr     = (const float*)d_in[24];
    const float* l1_We     = (const float*)d_in[25];
    const float* l1_att    = (const float*)d_in[26];
    const float* l1_b      = (const float*)d_in[27];
    const float* l1_bn_g   = (const float*)d_in[28];
    const float* l1_bn_b   = (const float*)d_in[29];
    const float* fc2_W     = (const float*)d_in[30];
    const float* fc2_b     = (const float*)d_in[31];

    const int* src = edge_idx;
    const int* dst = edge_idx + NE;

    float* ws     = (float*)d_ws;
    float* h0     = ws;                       // 64*NN f32
    float* X      = h0 + (size_t)64 * NN;     // 256*NN f32
    float* Y      = X + (size_t)HC * NN;      // 256*NN f32
    float* V      = Y + (size_t)HC * NN;      // 256*NN f32
    float* stats0 = V + (size_t)HC * NN;      // 512
    float* stats1 = stats0 + 512;             // 512
    float* ea_s   = stats1 + 512;             // 8*NE f32
    int* row_start = (int*)(ea_s + (size_t)8 * NE);  // NN
    int* row_cnt   = row_start + NN;                 // NN
    int* ssd       = row_cnt + NN;                   // NE
    short* hn_b    = (short*)(ssd + NE);             // 64*NN bf16
    short* Wt0     = hn_b + (size_t)64 * NN;         // 512*64 bf16
    short* Wt1     = Wt0 + 512 * 64;                 // 512*256 bf16

    float* out = (float*)d_out;

    k_front<<<NN / 4 + NGRAPH + 1024, 256, 0, stream>>>(
        x, node_grp, group_emb, W_embed, b_embed, h0,
        src, dst, edge_attr, row_start, row_cnt, ssd, ea_s, stats0,
        l0_Wl, l0_Wr, l1_Wl, l1_Wr, Wt0, Wt1);
    k_gine_mlp_ln<<<NN / 4, 256, 0, stream>>>(h0, row_start, row_cnt, ssd, ea_s,
                                              We_enc, be_enc, W1, b1, W2, b2, ln_g, ln_b, hn_b);

    // GAT layer 0
    k_gemm<64, false><<<NN / 16, 256, 0, stream>>>(hn_b, nullptr, nullptr, nullptr, nullptr,
                                                   Wt0, X, Y);
    k_gat<<<NGRAPH * 8, 256, 0, stream>>>(row_start, row_cnt, ssd, ea_s,
                                          l0_We, l0_att, l0_b, X, Y, V, stats0);

    // GAT layer 1 (BN+leaky+bf16 of layer-0 output fused into GEMM A-load)
    k_gemm<256, true><<<NN / 16, 256, 0, stream>>>(nullptr, V, stats0, l0_bn_g, l0_bn_b,
                                                   Wt1, X, Y);
    k_gat<<<NGRAPH * 8, 256, 0, stream>>>(row_start, row_cnt, ssd, ea_s,
                                          l1_We, l1_att, l1_b, X, Y, V, stats1);

    // BN+leaky of layer-1 output fused into pooling
    k_pool_fc<<<NGRAPH, 256, 0, stream>>>(V, stats1, l1_bn_g, l1_bn_b, fc2_W, fc2_b, out);
}

// Round 11
// 425.582 us; speedup vs baseline: 1.2655x; 1.0105x over previous
//
#include <hip/hip_runtime.h>
#include <hip/hip_bf16.h>

#define NN     14848      // nodes
#define NE     475136     // edges
#define NROI   116        // nodes per graph
#define NGRAPH 128        // graphs
#define EPG    3712       // edges per graph (116*32)
#define HID    64
#define HC     256
#define NEG    0.01f
#define NEGA   0.2f
#define EPB    2304       // max edges per half-graph block (mean 1856)
#define XPADB  66         // Xs (bf16) row stride: even (4B-aligned pairs), 66/2=33 odd dwords -> bank rotation

typedef __attribute__((ext_vector_type(8))) short short8;
typedef __attribute__((ext_vector_type(4))) float floatx4;
typedef __attribute__((ext_vector_type(2))) float floatx2;

// leaky(x) = max(x, s*x) for 0<s<1 — 2 VALU, no branch
__device__ __forceinline__ float leaky(float x, float s) { return fmaxf(x, s * x); }

// round-to-nearest-even float -> bf16 bits
__device__ __forceinline__ short f2bf(float f) {
    unsigned u = __float_as_uint(f);
    unsigned r = (u + 0x7fffu + ((u >> 16) & 1u)) >> 16;
    return (short)r;
}
__device__ __forceinline__ float bf2f(unsigned short b) {
    return __uint_as_float((unsigned)b << 16);
}

// ---------------------------------------------------------------- front: embed + CSR + weight prep (independent; one dispatch)
__global__ __launch_bounds__(256) void k_front(
    const float* __restrict__ x, const int* __restrict__ ng,
    const float* __restrict__ gemb, const float* __restrict__ W,
    const float* __restrict__ b, float* __restrict__ h0,
    const int* __restrict__ src, const int* __restrict__ dst,
    const float* __restrict__ ea,
    int* __restrict__ row_start, int* __restrict__ row_cnt,
    int* __restrict__ ssd, float* __restrict__ ea_s,
    float* __restrict__ stats01,
    const float* __restrict__ Wl0, const float* __restrict__ Wr0,
    const float* __restrict__ Wl1, const float* __restrict__ Wr1,
    short* __restrict__ Wt0, short* __restrict__ Wt1)
{
    const int tid = threadIdx.x;
    if (blockIdx.x < NN / 4) {
        // ---- embed
        const int w = tid >> 6, c = tid & 63;
        const int n = blockIdx.x * 4 + w;
        __shared__ float in[4][132];
        for (int k = c; k < NROI; k += 64) in[w][k] = x[n * NROI + k];
        if (c < 16) in[w][NROI + c] = gemb[ng[n] * 16 + c];
        __syncthreads();
        float acc = b[c];
        #pragma unroll 4
        for (int k = 0; k < 132; k++) acc = fmaf(in[w][k], W[k * 64 + c], acc);
        h0[n * 64 + c] = leaky(acc, NEG);
    } else if (blockIdx.x < NN / 4 + NGRAPH) {
        // ---- CSR
        const int g = blockIdx.x - NN / 4;
        if (g < 2) {
            for (int i = tid; i < 512; i += 256) stats01[g * 512 + i] = 0.f;
        }
        const int e0 = g * EPG, nb = g * NROI;
        __shared__ int cnt[NROI], start[NROI], cur[NROI];
        if (tid < NROI) cnt[tid] = 0;
        __syncthreads();
        for (int i = tid; i < EPG; i += 256) atomicAdd(&cnt[dst[e0 + i] - nb], 1);
        __syncthreads();
        if (tid == 0) {
            int s = 0;
            for (int r = 0; r < NROI; r++) { start[r] = s; s += cnt[r]; }
        }
        __syncthreads();
        if (tid < NROI) {
            row_start[nb + tid] = e0 + start[tid];
            row_cnt[nb + tid] = cnt[tid];
            cur[tid] = start[tid];
        }
        __syncthreads();
        for (int i = tid; i < EPG; i += 256) {
            const int e = e0 + i, dl = dst[e] - nb;
            const int pos = atomicAdd(&cur[dl], 1);
            const int gi = e0 + pos;
            ssd[gi] = (src[e] - nb) | (dl << 16);
            const float4 q = make_float4(ea[e * 5], ea[e * 5 + 1], ea[e * 5 + 2], ea[e * 5 + 3]);
            *(float4*)&ea_s[(size_t)gi * 8] = q;
            ea_s[(size_t)gi * 8 + 4] = ea[e * 5 + 4];
        }
    } else {
        // ---- weight prep
        const int bb = blockIdx.x - (NN / 4 + NGRAPH);
        if (bb < 512) {
            const int n = bb;
            for (int k = tid; k < 64; k += 256) {
                const float v = (n < 256) ? Wl0[k * 256 + n] : Wr0[k * 256 + (n - 256)];
                Wt0[(size_t)n * 64 + k] = f2bf(v);
            }
        } else {
            const int n = bb - 512;
            for (int k = tid; k < 256; k += 256) {
                const float v = (n < 256) ? Wl1[k * 256 + n] : Wr1[k * 256 + (n - 256)];
                Wt1[(size_t)n * 256 + k] = f2bf(v);
            }
        }
    }
}

// ---------------------------------------------------------------- GINE (CSR, per-row wave) fused with MLP + LayerNorm -> bf16
__global__ __launch_bounds__(256) void k_gine_mlp_ln(
    const float* __restrict__ h0, const int* __restrict__ row_start,
    const int* __restrict__ row_cnt, const int* __restrict__ ssd,
    const float* __restrict__ ea_s,
    const float* __restrict__ We, const float* __restrict__ be,
    const float* __restrict__ W1, const float* __restrict__ b1,
    const float* __restrict__ W2, const float* __restrict__ b2,
    const float* __restrict__ lg_, const float* __restrict__ lb_,
    short* __restrict__ hn)
{
    const int tid = threadIdx.x, w = tid >> 6, lane = tid & 63;
    const int row = blockIdx.x * 4 + w;
    const int nb = (row / NROI) * NROI;
    const int st = row_start[row], cnt = row_cnt[row];
    const float w0 = We[lane], w1 = We[64 + lane], w2 = We[128 + lane],
                w3 = We[192 + lane], w4 = We[256 + lane];
    const float bec = be[lane];
    float g0 = 0.f, g1 = 0.f, g2 = 0.f, g3 = 0.f;
    int j = 0;
    for (; j + 4 <= cnt; j += 4) {
        const int i0 = st + j, i1 = st + j + 1, i2 = st + j + 2, i3 = st + j + 3;
        const int s0 = nb + (ssd[i0] & 0xffff), s1 = nb + (ssd[i1] & 0xffff),
                  s2 = nb + (ssd[i2] & 0xffff), s3 = nb + (ssd[i3] & 0xffff);
        const float h_0 = h0[s0 * 64 + lane], h_1 = h0[s1 * 64 + lane],
                    h_2 = h0[s2 * 64 + lane], h_3 = h0[s3 * 64 + lane];
        const float4 qa = *(const float4*)&ea_s[(size_t)i0 * 8];
        const float qa4 = ea_s[(size_t)i0 * 8 + 4];
        const float4 qb = *(const float4*)&ea_s[(size_t)i1 * 8];
        const float qb4 = ea_s[(size_t)i1 * 8 + 4];
        const float4 qc = *(const float4*)&ea_s[(size_t)i2 * 8];
        const float qc4 = ea_s[(size_t)i2 * 8 + 4];
        const float4 qd = *(const float4*)&ea_s[(size_t)i3 * 8];
        const float qd4 = ea_s[(size_t)i3 * 8 + 4];
        float e0_ = bec, e1_ = bec, e2_ = bec, e3_ = bec;
        e0_ = fmaf(qa.x, w0, e0_); e1_ = fmaf(qb.x, w0, e1_);
        e2_ = fmaf(qc.x, w0, e2_); e3_ = fmaf(qd.x, w0, e3_);
        e0_ = fmaf(qa.y, w1, e0_); e1_ = fmaf(qb.y, w1, e1_);
        e2_ = fmaf(qc.y, w1, e2_); e3_ = fmaf(qd.y, w1, e3_);
        e0_ = fmaf(qa.z, w2, e0_); e1_ = fmaf(qb.z, w2, e1_);
        e2_ = fmaf(qc.z, w2, e2_); e3_ = fmaf(qd.z, w2, e3_);
        e0_ = fmaf(qa.w, w3, e0_); e1_ = fmaf(qb.w, w3, e1_);
        e2_ = fmaf(qc.w, w3, e2_); e3_ = fmaf(qd.w, w3, e3_);
        e0_ = fmaf(qa4, w4, e0_);  e1_ = fmaf(qb4, w4, e1_);
        e2_ = fmaf(qc4, w4, e2_);  e3_ = fmaf(qd4, w4, e3_);
        g0 += fmaxf(h_0 + leaky(e0_, NEG), 0.f);
        g1 += fmaxf(h_1 + leaky(e1_, NEG), 0.f);
        g2 += fmaxf(h_2 + leaky(e2_, NEG), 0.f);
        g3 += fmaxf(h_3 + leaky(e3_, NEG), 0.f);
    }
    for (; j < cnt; j++) {
        const int idx = st + j;
        const int s = nb + (ssd[idx] & 0xffff);
        const float4 q = *(const float4*)&ea_s[(size_t)idx * 8];
        const float q4 = ea_s[(size_t)idx * 8 + 4];
        float em = bec;
        em = fmaf(q.x, w0, em); em = fmaf(q.y, w1, em); em = fmaf(q.z, w2, em);
        em = fmaf(q.w, w3, em); em = fmaf(q4, w4, em);
        g0 += fmaxf(h0[s * 64 + lane] + leaky(em, NEG), 0.f);
    }
    const float aggv = (g0 + g1) + (g2 + g3);
    __shared__ float v[4][64], t[4][64];
    v[w][lane] = h0[row * 64 + lane] + aggv;
    __syncthreads();
    float a = b1[lane];
    #pragma unroll 8
    for (int k = 0; k < 64; k++) a = fmaf(v[w][k], W1[k * 64 + lane], a);
    t[w][lane] = leaky(a, NEG);
    __syncthreads();
    float o = b2[lane];
    #pragma unroll 8
    for (int k = 0; k < 64; k++) o = fmaf(t[w][k], W2[k * 64 + lane], o);
    o = leaky(o, NEG);
    float s = o;
    #pragma unroll
    for (int off = 32; off; off >>= 1) s += __shfl_xor(s, off);
    const float mu = s * (1.f / 64.f);
    const float d = o - mu;
    float s2 = d * d;
    #pragma unroll
    for (int off = 32; off; off >>= 1) s2 += __shfl_xor(s2, off);
    hn[row * 64 + lane] = f2bf(d * rsqrtf(s2 * (1.f / 64.f) + 1e-5f) * lg_[lane] + lb_[lane]);
}

// ---------------------------------------------------------------- MFMA bf16 GEMM: [NN x D] @ [D x 512] -> X | Y (fp32)
template <int D, bool BN>
__global__ __launch_bounds__(256) void k_gemm(
    const short* __restrict__ A, const float* __restrict__ Vin,
    const float* __restrict__ stats, const float* __restrict__ bn_g,
    const float* __restrict__ bn_b,
    const short* __restrict__ Wt,
    float* __restrict__ X, float* __restrict__ Y)
{
    const int m0 = blockIdx.x * 16;
    const int w = threadIdx.x >> 6, lane = threadIdx.x & 63;
    const int n0 = w * 128;                     // waves 0,1 -> X; 2,3 -> Y
    const int r = lane & 15, q = lane >> 4;
    __shared__ float sc_s[256], sh_s[256];
    if constexpr (BN) {
        const int c = threadIdx.x;
        const float inv_n = 1.f / (float)NN;
        const float mu = stats[c] * inv_n;
        float var = stats[256 + c] * inv_n - mu * mu;
        var = fmaxf(var, 0.f);
        const float rsg = rsqrtf(var + 1e-5f) * bn_g[c];
        sc_s[c] = rsg;
        sh_s[c] = bn_b[c] - mu * rsg;
        __syncthreads();
    }
    floatx4 acc[8];
    #pragma unroll
    for (int t = 0; t < 8; t++) acc[t] = (floatx4){0.f, 0.f, 0.f, 0.f};
    const short* Arow = A + (size_t)(m0 + r) * D + q * 8;
    const float* Vrow = Vin + (size_t)(m0 + r) * D + q * 8;
    const short* Brow = Wt + (size_t)(n0 + r) * D + q * 8;
    #pragma unroll
    for (int k0 = 0; k0 < D; k0 += 32) {
        short8 a;
        if constexpr (BN) {
            const float4 v0 = *(const float4*)(Vrow + k0);
            const float4 v1 = *(const float4*)(Vrow + k0 + 4);
            const int cb = q * 8 + k0;
            a[0] = f2bf(leaky(fmaf(v0.x, sc_s[cb + 0], sh_s[cb + 0]), NEG));
            a[1] = f2bf(leaky(fmaf(v0.y, sc_s[cb + 1], sh_s[cb + 1]), NEG));
            a[2] = f2bf(leaky(fmaf(v0.z, sc_s[cb + 2], sh_s[cb + 2]), NEG));
            a[3] = f2bf(leaky(fmaf(v0.w, sc_s[cb + 3], sh_s[cb + 3]), NEG));
            a[4] = f2bf(leaky(fmaf(v1.x, sc_s[cb + 4], sh_s[cb + 4]), NEG));
            a[5] = f2bf(leaky(fmaf(v1.y, sc_s[cb + 5], sh_s[cb + 5]), NEG));
            a[6] = f2bf(leaky(fmaf(v1.z, sc_s[cb + 6], sh_s[cb + 6]), NEG));
            a[7] = f2bf(leaky(fmaf(v1.w, sc_s[cb + 7], sh_s[cb + 7]), NEG));
        } else {
            a = *(const short8*)(Arow + k0);
        }
        #pragma unroll
        for (int t = 0; t < 8; t++) {
            const short8 b = *(const short8*)(Brow + (size_t)t * 16 * D + k0);
            acc[t] = __builtin_amdgcn_mfma_f32_16x16x32_bf16(a, b, acc[t], 0, 0, 0);
        }
    }
    #pragma unroll
    for (int t = 0; t < 8; t++) {
        const int ncol = n0 + t * 16 + r;
        #pragma unroll
        for (int g2 = 0; g2 < 4; g2++) {
            const int row = m0 + q * 4 + g2;
            if (ncol < 256) X[(size_t)row * HC + ncol] = acc[t][g2];
            else            Y[(size_t)row * HC + (ncol - 256)] = acc[t][g2];
        }
    }
}

// ---------------------------------------------------------------- fused GATv2: XCD-swizzled, bf16 Xs (24.7 KB LDS -> 6 blocks/CU)
// blockIdx = sub*128 + g: all 8 blocks of graph g share blockIdx%8 -> same XCD L2
__global__ __launch_bounds__(256, 6) void k_gat(
    const int* __restrict__ row_start, const int* __restrict__ row_cnt,
    const int* __restrict__ ssd, const float* __restrict__ ea_s,
    const float* __restrict__ We, const float* __restrict__ att,
    const float* __restrict__ bias,
    const float* __restrict__ X, const float* __restrict__ Y,
    float* __restrict__ V, float* __restrict__ stats)
{
    const int g = blockIdx.x & 127;
    const int sub = blockIdx.x >> 7;
    const int h = sub >> 1;
    const int half = sub & 1;
    const int tid = threadIdx.x, w = tid >> 6, lane = tid & 63;
    const int nb = g * NROI, e0 = g * EPG, hc = h * 64;
    const int r0 = half * 58, r1 = r0 + 58;
    const int es = row_start[nb + r0];
    const int ee = (r1 < NROI) ? row_start[nb + r1] : e0 + EPG;

    __shared__ short Xs[NROI * XPADB];   // bf16 X head-slice: 15.3 KB
    __shared__ float lg[EPB];
    __shared__ float inv_s[58];

    for (int r = w; r < NROI; r += 4)
        Xs[r * XPADB + lane] = f2bf(X[(size_t)(nb + r) * HC + hc + lane]);
    __syncthreads();

    // ---- phase A: logits, lane = edge, packed-f32 pairs (R9-measured-best loop)
    const int ne = ee - es;
    for (int i = tid; i < ne; i += 256) {
        const int e = es + i;
        const int sd = ssd[e];
        const int sl = sd & 0xffff, dl = sd >> 16;
        const float4 q = *(const float4*)&ea_s[(size_t)e * 8];
        const float q4 = ea_s[(size_t)e * 8 + 4];
        const floatx2 qx = {q.x, q.x}, qy = {q.y, q.y}, qz = {q.z, q.z},
                      qw = {q.w, q.w}, qv = {q4, q4};
        const float* yrow = &Y[(size_t)(nb + dl) * HC + hc];
        const unsigned* xrow = (const unsigned*)&Xs[sl * XPADB];  // 4B-aligned (even stride)
        floatx2 lacc = {0.f, 0.f};
        #pragma unroll 8
        for (int c = 0; c < 64; c += 2) {
            const floatx2 y2 = *(const floatx2*)(yrow + c);        // 8B-aligned
            const unsigned xp = xrow[c >> 1];                      // 2 bf16 in one dword
            const floatx2 xs2 = {__uint_as_float(xp << 16),
                                 __uint_as_float(xp & 0xffff0000u)};
            const floatx2 w0 = *(const floatx2*)(We + 0 * HC + hc + c);
            const floatx2 w1 = *(const floatx2*)(We + 1 * HC + hc + c);
            const floatx2 w2 = *(const floatx2*)(We + 2 * HC + hc + c);
            const floatx2 w3 = *(const floatx2*)(We + 3 * HC + hc + c);
            const floatx2 w4 = *(const floatx2*)(We + 4 * HC + hc + c);
            floatx2 ep = qx * w0;
            ep += qy * w1;
            ep += qz * w2;
            ep += qw * w3;
            ep += qv * w4;
            const floatx2 z = xs2 + y2 + ep;
            const floatx2 zs = z * (floatx2){NEGA, NEGA};
            const floatx2 lk = {fmaxf(z.x, zs.x), fmaxf(z.y, zs.y)};
            const floatx2 a2 = *(const floatx2*)(att + hc + c);
            lacc += a2 * lk;
        }
        lg[i] = lacc.x + lacc.y;
    }
    __syncthreads();

    // ---- phase B: per-row max / exp / sum; store reciprocal
    for (int r = r0 + w; r < r1; r += 4) {
        const int stl = row_start[nb + r] - es;
        const int cnt = row_cnt[nb + r];
        float m = -INFINITY;
        for (int j = lane; j < cnt; j += 64) m = fmaxf(m, lg[stl + j]);
        #pragma unroll
        for (int off = 32; off; off >>= 1) m = fmaxf(m, __shfl_xor(m, off));
        float s = 0.f;
        for (int j = lane; j < cnt; j += 64) {
            const float e_ = __expf(lg[stl + j] - m);
            lg[stl + j] = e_;
            s += e_;
        }
        #pragma unroll
        for (int off = 32; off; off >>= 1) s += __shfl_xor(s, off);
        if (lane == 0) inv_s[r - r0] = 1.f / (s + 1e-16f);
    }
    __syncthreads();

    // ---- phase C: numerator (wave per row, lane = channel) + BN partials
    float ps = 0.f, ps2 = 0.f;
    const float bb = bias[hc + lane];
    for (int r = r0 + w; r < r1; r += 4) {
        const int st = row_start[nb + r];
        const int cnt = row_cnt[nb + r];
        const int stl = st - es;
        float a0 = 0.f, a1 = 0.f, a2 = 0.f, a3 = 0.f;
        int j = 0;
        for (; j + 4 <= cnt; j += 4) {
            const int s0 = ssd[st + j] & 0xffff, s1 = ssd[st + j + 1] & 0xffff,
                      s2 = ssd[st + j + 2] & 0xffff, s3 = ssd[st + j + 3] & 0xffff;
            a0 = fmaf(bf2f((unsigned short)Xs[s0 * XPADB + lane]), lg[stl + j], a0);
            a1 = fmaf(bf2f((unsigned short)Xs[s1 * XPADB + lane]), lg[stl + j + 1], a1);
            a2 = fmaf(bf2f((unsigned short)Xs[s2 * XPADB + lane]), lg[stl + j + 2], a2);
            a3 = fmaf(bf2f((unsigned short)Xs[s3 * XPADB + lane]), lg[stl + j + 3], a3);
        }
        for (; j < cnt; j++)
            a0 = fmaf(bf2f((unsigned short)Xs[(ssd[st + j] & 0xffff) * XPADB + lane]),
                      lg[stl + j], a0);
        const float vv = ((a0 + a1) + (a2 + a3)) * inv_s[r - r0] + bb;
        V[(size_t)(nb + r) * HC + hc + lane] = vv;
        ps += vv;
        ps2 += vv * vv;
    }
    __syncthreads();                 // lg free; reuse as reduction buffer
    lg[tid] = ps;
    lg[256 + tid] = ps2;
    __syncthreads();
    if (tid < 64) {
        float s1 = 0.f, s2 = 0.f;
        #pragma unroll
        for (int w2 = 0; w2 < 4; w2++) {
            s1 += lg[w2 * 64 + tid];
            s2 += lg[256 + w2 * 64 + tid];
        }
        atomicAdd(&stats[hc + tid], s1);
        atomicAdd(&stats[256 + hc + tid], s2);
    }
}

// ---------------------------------------------------------------- BN + leaky + mean-pool + classifier
__global__ __launch_bounds__(256) void k_pool_fc(
    const float* __restrict__ V, const float* __restrict__ stats,
    const float* __restrict__ bg, const float* __restrict__ bb,
    const float* __restrict__ fW, const float* __restrict__ fb,
    float* __restrict__ out)
{
    const int g = blockIdx.x, c = threadIdx.x;
    const float inv_n = 1.f / (float)NN;
    const float mu = stats[c] * inv_n;
    float var = stats[256 + c] * inv_n - mu * mu;
    var = fmaxf(var, 0.f);
    const float rsg = rsqrtf(var + 1e-5f) * bg[c];
    const float bbc = bb[c];
    float s = 0.f;
    for (int r = 0; r < NROI; r++) {
        const float vv = (V[(size_t)(g * NROI + r) * HC + c] - mu) * rsg + bbc;
        s += leaky(vv, NEG);
    }
    s *= (1.f / (float)NROI);
    __shared__ float red[256];
    for (int o = 0; o < 2; o++) {
        red[c] = s * fW[c * 2 + o];
        __syncthreads();
        for (int off = 128; off; off >>= 1) {
            if (c < off) red[c] += red[c + off];
            __syncthreads();
        }
        if (c == 0) out[g * 2 + o] = red[0] + fb[o];
        __syncthreads();
    }
}

extern "C" void kernel_launch(void* const* d_in, const int* in_sizes, int n_in,
                              void* d_out, int out_size, void* d_ws, size_t ws_size,
                              hipStream_t stream) {
    const float* x         = (const float*)d_in[0];
    const int*   edge_idx  = (const int*)d_in[1];
    const float* edge_attr = (const float*)d_in[2];
    const int*   node_grp  = (const int*)d_in[4];
    const float* group_emb = (const float*)d_in[5];
    const float* W_embed   = (const float*)d_in[6];
    const float* b_embed   = (const float*)d_in[7];
    const float* We_enc    = (const float*)d_in[8];
    const float* be_enc    = (const float*)d_in[9];
    const float* W1        = (const float*)d_in[10];
    const float* b1        = (const float*)d_in[11];
    const float* W2        = (const float*)d_in[12];
    const float* b2        = (const float*)d_in[13];
    const float* ln_g      = (const float*)d_in[14];
    const float* ln_b      = (const float*)d_in[15];
    const float* l0_Wl     = (const float*)d_in[16];
    const float* l0_Wr     = (const float*)d_in[17];
    const float* l0_We     = (const float*)d_in[18];
    const float* l0_att    = (const float*)d_in[19];
    const float* l0_b      = (const float*)d_in[20];
    const float* l0_bn_g   = (const float*)d_in[21];
    const float* l0_bn_b   = (const float*)d_in[22];
    const float* l1_Wl     = (const float*)d_in[23];
    const float* l1_Wr     = (const float*)d_in[24];
    const float* l1_We     = (const float*)d_in[25];
    const float* l1_att    = (const float*)d_in[26];
    const float* l1_b      = (const float*)d_in[27];
    const float* l1_bn_g   = (const float*)d_in[28];
    const float* l1_bn_b   = (const float*)d_in[29];
    const float* fc2_W     = (const float*)d_in[30];
    const float* fc2_b     = (const float*)d_in[31];

    const int* src = edge_idx;
    const int* dst = edge_idx + NE;

    float* ws     = (float*)d_ws;
    float* h0     = ws;                       // 64*NN f32
    float* X      = h0 + (size_t)64 * NN;     // 256*NN f32
    float* Y      = X + (size_t)HC * NN;      // 256*NN f32
    float* V      = Y + (size_t)HC * NN;      // 256*NN f32
    float* stats0 = V + (size_t)HC * NN;      // 512
    float* stats1 = stats0 + 512;             // 512
    float* ea_s   = stats1 + 512;             // 8*NE f32
    int* row_start = (int*)(ea_s + (size_t)8 * NE);  // NN
    int* row_cnt   = row_start + NN;                 // NN
    int* ssd       = row_cnt + NN;                   // NE
    short* hn_b    = (short*)(ssd + NE);             // 64*NN bf16
    short* Wt0     = hn_b + (size_t)64 * NN;         // 512*64 bf16
    short* Wt1     = Wt0 + 512 * 64;                 // 512*256 bf16

    float* out = (float*)d_out;

    k_front<<<NN / 4 + NGRAPH + 1024, 256, 0, stream>>>(
        x, node_grp, group_emb, W_embed, b_embed, h0,
        src, dst, edge_attr, row_start, row_cnt, ssd, ea_s, stats0,
        l0_Wl, l0_Wr, l1_Wl, l1_Wr, Wt0, Wt1);
    k_gine_mlp_ln<<<NN / 4, 256, 0, stream>>>(h0, row_start, row_cnt, ssd, ea_s,
                                              We_enc, be_enc, W1, b1, W2, b2, ln_g, ln_b, hn_b);

    // GAT layer 0
    k_gemm<64, false><<<NN / 16, 256, 0, stream>>>(hn_b, nullptr, nullptr, nullptr, nullptr,
                                                   Wt0, X, Y);
    k_gat<<<NGRAPH * 8, 256, 0, stream>>>(row_start, row_cnt, ssd, ea_s,
                                          l0_We, l0_att, l0_b, X, Y, V, stats0);

    // GAT layer 1 (BN+leaky+bf16 of layer-0 output fused into GEMM A-load)
    k_gemm<256, true><<<NN / 16, 256, 0, stream>>>(nullptr, V, stats0, l0_bn_g, l0_bn_b,
                                                   Wt1, X, Y);
    k_gat<<<NGRAPH * 8, 256, 0, stream>>>(row_start, row_cnt, ssd, ea_s,
                                          l1_We, l1_att, l1_b, X, Y, V, stats1);

    // BN+leaky of layer-1 output fused into pooling
    k_pool_fc<<<NGRAPH, 256, 0, stream>>>(V, stats1, l1_bn_g, l1_bn_b, fc2_W, fc2_b, out);
}